// Round 2
// baseline (274.292 us; speedup 1.0000x reference)
//
#include <hip/hip_runtime.h>

typedef unsigned short u16;
typedef __attribute__((ext_vector_type(8))) short bf16x8;
typedef __attribute__((ext_vector_type(4))) float f32x4;

#define B_DIM 4096
#define D_DIM 512
#define H_DIM 16

typedef const __attribute__((address_space(1))) unsigned int* gas_t;
typedef __attribute__((address_space(3))) unsigned int* las_t;

__device__ __forceinline__ u16 f2bf(float f) {
  union { float f; unsigned u; } x;
  x.f = f;
  unsigned r = x.u + 0x7FFFu + ((x.u >> 16) & 1u);
  return (u16)(r >> 16);
}

__device__ __forceinline__ uint4 pack8(float4 v0, float4 v1) {
  union { uint4 q; u16 h[8]; } u;
  u.h[0] = f2bf(v0.x); u.h[1] = f2bf(v0.y); u.h[2] = f2bf(v0.z); u.h[3] = f2bf(v0.w);
  u.h[4] = f2bf(v1.x); u.h[5] = f2bf(v1.y); u.h[6] = f2bf(v1.z); u.h[7] = f2bf(v1.w);
  return u.q;
}

// ---- prep uber kernel ----
// kind 0: 64x64 LDS transpose f32->bf16 (optional out2 = row-major bf16 copy);
// kind 1: transpose with lam(conf) row-scale; kind 2: count reduction (1 block);
// kind 3: zero f32 (4096 floats/block).
struct TJob {
  const float* in;
  void* out;
  void* out2;
  const float* conf;
  int rows, cols, tiles_x, tile_off, kind;
};
struct TJobs { TJob j[10]; };

__global__ __launch_bounds__(256) void mega_prep(TJobs J, float* __restrict__ countp) {
  __shared__ float tile[64][65];
  __shared__ float wsum[4];
  const int tid = threadIdx.x;
  int b = blockIdx.x;
  int sel = 0;
#pragma unroll
  for (int i = 1; i < 10; ++i)
    if (b >= J.j[i].tile_off) sel = i;
  TJob jb = J.j[sel];
  b -= jb.tile_off;

  if (jb.kind == 3) {  // zero f32
    long long base = (long long)b * 4096 + tid * 16;
    float4 z = {0.f, 0.f, 0.f, 0.f};
    float* o = (float*)jb.out + base;
    *(float4*)o = z; *(float4*)(o + 4) = z; *(float4*)(o + 8) = z; *(float4*)(o + 12) = z;
    return;
  }
  if (jb.kind == 2) {  // count
    float m = 0.f;
    for (int i = tid; i < B_DIM; i += 256) {
      float l = 1.0f - jb.in[i];
      l = fminf(fmaxf(l, 0.f), 1.f);
      m += (l > 0.3f) ? 1.f : 0.f;
    }
    for (int off = 32; off; off >>= 1) m += __shfl_down(m, off, 64);
    if ((tid & 63) == 0) wsum[tid >> 6] = m;
    __syncthreads();
    if (tid == 0) countp[0] = wsum[0] + wsum[1] + wsum[2] + wsum[3];
    return;
  }

  // transpose kinds 0/1: 64x64 tile via LDS.
  // read: float4/lane coalesced rows; write: 32 B/lane contiguous u16 rows.
  const long long c0 = (long long)(b % jb.tiles_x) * 64;
  const long long r0 = (long long)(b / jb.tiles_x) * 64;
  const int rr = tid >> 4;         // 0..15
  const int cc4 = (tid & 15) * 4;  // 0..60
#pragma unroll
  for (int i = 0; i < 4; ++i) {
    int row = i * 16 + rr;
    float4 v = *(const float4*)(jb.in + (r0 + row) * jb.cols + c0 + cc4);
    if (jb.kind == 1) {
      float l = 1.0f - jb.conf[r0 + row];
      l = fminf(fmaxf(l, 0.f), 1.f);
      float s = (l > 0.3f) ? l : 0.f;
      v.x *= s; v.y *= s; v.z *= s; v.w *= s;
    }
    tile[row][cc4] = v.x; tile[row][cc4 + 1] = v.y;
    tile[row][cc4 + 2] = v.z; tile[row][cc4 + 3] = v.w;
    if (jb.out2) {  // row-major bf16 side copy (Wk: saves a second 16 MB pass)
      union { uint2 u; u16 h[4]; } p;
      p.h[0] = f2bf(v.x); p.h[1] = f2bf(v.y); p.h[2] = f2bf(v.z); p.h[3] = f2bf(v.w);
      *(uint2*)((u16*)jb.out2 + (r0 + row) * jb.cols + c0 + cc4) = p.u;
    }
  }
  __syncthreads();
  const int orow = tid >> 2;  // 0..63  (output row = input column)
  const int seg = tid & 3;    // 16 u16 per thread
  union { uint4 q[2]; u16 h[16]; } o;
#pragma unroll
  for (int i = 0; i < 16; ++i) o.h[i] = f2bf(tile[seg * 16 + i][orow]);
  u16* outp = (u16*)jb.out + (c0 + orow) * jb.rows + r0 + seg * 16;
  *(uint4*)outp = o.q[0];
  *(uint4*)(outp + 8) = o.q[1];
}

// ---- 128x128-tile GEMM, BK=64, double-buffered, swizzled LDS ----
// C(M,N) = alpha * A(M,K) @ Bt(N,K)^T, both k-contiguous. 4 waves, each 64x64.
// bf16 operands via global_load_lds(16B); f32 (aflag/bflag) via float4+pack+ds_write.
// LDS chunk swizzle: LDS[row][cl] holds G[row][cl ^ (row&7)] (chunks of 8 elems).
// Split-K: non-batched jobs use bz as k-chunk; batched jobs decompose bz into
// (batch, k-chunk) via bsplit (k-chunks per batch).
// mode 0: atomicAdd f32 * alpha (split-K); 1: store bf16*alpha; 2: store f32*alpha;
// 3: store f32 = addsrc + acc/(count+1e-6).
struct GJob {
  const void* A; const void* Bp; void* C;
  const float* addsrc; const float* cnt;
  long long lda, ldb, ldc, sa_b, sb_b, sc_b, sadd_b;
  float alpha;
  int K, k_chunk, tm, tn, batched, bsplit, mode, aflag, bflag, nblocks;
};
struct GJobs { GJob j[2]; };

__global__ __launch_bounds__(256, 2) void gemm128(GJobs JJ) {
  __shared__ alignas(16) u16 As[2][128 * 64];
  __shared__ alignas(16) u16 Bs[2][128 * 64];

  int b = blockIdx.x;
  GJob J = JJ.j[0];
  if (b >= J.nblocks) { b -= J.nblocks; J = JJ.j[1]; }

  const int tilesper = J.tm * J.tn;
  const int bz = b / tilesper;
  const int rel = b % tilesper;
  const long long m0 = (long long)(rel / J.tn) * 128;
  const long long n0 = (long long)(rel % J.tn) * 128;

  long long aoff = 0, boff = 0, coff = 0, doff = 0, k0 = 0;
  int Kl = J.K;
  if (J.batched) {
    const int zb = bz / J.bsplit;
    const int kc = bz - zb * J.bsplit;
    aoff = (long long)zb * J.sa_b;
    boff = (long long)zb * J.sb_b;
    coff = (long long)zb * J.sc_b;
    doff = (long long)zb * J.sadd_b;
    k0 = (long long)kc * J.k_chunk;
    Kl = J.k_chunk;
  } else {
    k0 = (long long)bz * J.k_chunk;
    Kl = J.k_chunk;
  }

  const int tid = threadIdx.x;
  const int lane = tid & 63, wave = tid >> 6;
  const int wm = (wave & 1) * 64, wn = (wave >> 1) * 64;
  const int fm = lane & 15, fg = lane >> 4;

  auto stage = [&](u16* dst, const void* src, long long ld, long long off,
                   long long rbase, long long t, int isf32) {
    if (!isf32) {
      const u16* gb = (const u16*)src + off;
#pragma unroll
      for (int j = 0; j < 4; ++j) {
        int cc = wave * 4 + j;
        int row = cc * 8 + (lane >> 3);
        int cg = (lane & 7) ^ (row & 7);
        const u16* g = gb + (rbase + row) * ld + t + cg * 8;
        __builtin_amdgcn_global_load_lds((gas_t)(const void*)g,
                                         (las_t)(void*)(dst + cc * 512 + lane * 8),
                                         16, 0, 0);
      }
    } else {
      const float* gb = (const float*)src + off;
#pragma unroll
      for (int p = 0; p < 4; ++p) {
        int idx = p * 256 + tid;
        int row = idx >> 3, cg = idx & 7;
        const float* g = gb + (rbase + row) * ld + t + cg * 8;
        float4 v0 = *(const float4*)g;
        float4 v1 = *(const float4*)(g + 4);
        *(uint4*)&dst[row * 64 + ((cg ^ (row & 7)) * 8)] = pack8(v0, v1);
      }
    }
  };

  f32x4 acc[4][4];
#pragma unroll
  for (int i = 0; i < 4; ++i)
#pragma unroll
    for (int j = 0; j < 4; ++j) acc[i][j] = (f32x4){0.f, 0.f, 0.f, 0.f};

  const int nIter = Kl >> 6;
  stage(As[0], J.A, J.lda, aoff, m0, k0, J.aflag);
  stage(Bs[0], J.Bp, J.ldb, boff, n0, k0, J.bflag);

  for (int i = 0; i < nIter; ++i) {
    __syncthreads();  // drains current buffer's loads
    if (i + 1 < nIter) {
      long long t = k0 + (long long)(i + 1) * 64;
      stage(As[(i + 1) & 1], J.A, J.lda, aoff, m0, t, J.aflag);
      stage(Bs[(i + 1) & 1], J.Bp, J.ldb, boff, n0, t, J.bflag);
    }
    const u16* Ab = As[i & 1];
    const u16* Bb = Bs[i & 1];
#pragma unroll
    for (int kcc = 0; kcc < 8; kcc += 4) {
      bf16x8 af[4], bfr[4];
#pragma unroll
      for (int fi = 0; fi < 4; ++fi) {
        int row = wm + fi * 16 + fm;
        af[fi] = *(const bf16x8*)&Ab[row * 64 + (((kcc + fg) ^ (row & 7)) * 8)];
      }
#pragma unroll
      for (int fj = 0; fj < 4; ++fj) {
        int row = wn + fj * 16 + fm;
        bfr[fj] = *(const bf16x8*)&Bb[row * 64 + (((kcc + fg) ^ (row & 7)) * 8)];
      }
#pragma unroll
      for (int fi = 0; fi < 4; ++fi)
#pragma unroll
        for (int fj = 0; fj < 4; ++fj)
          acc[fi][fj] = __builtin_amdgcn_mfma_f32_16x16x32_bf16(af[fi], bfr[fj], acc[fi][fj], 0, 0, 0);
    }
  }

  float inv = (J.mode == 3) ? 1.0f / (*J.cnt + 1e-6f) : 0.0f;
#pragma unroll
  for (int fi = 0; fi < 4; ++fi) {
#pragma unroll
    for (int r = 0; r < 4; ++r) {
      long long row = m0 + wm + fi * 16 + fg * 4 + r;
#pragma unroll
      for (int fj = 0; fj < 4; ++fj) {
        long long col = n0 + wn + fj * 16 + fm;
        long long idx = row * J.ldc + col;
        float v = acc[fi][fj][r];
        if (J.mode == 0) {
          atomicAdd((float*)J.C + coff + idx, v * J.alpha);
        } else if (J.mode == 1) {
          ((u16*)J.C)[coff + idx] = f2bf(v * J.alpha);
        } else if (J.mode == 2) {
          ((float*)J.C)[coff + idx] = v * J.alpha;
        } else {
          ((float*)J.C)[coff + idx] = J.addsrc[doff + idx] + v * inv;
        }
      }
    }
  }
}

extern "C" void kernel_launch(void* const* d_in, const int* in_sizes, int n_in,
                              void* d_out, int out_size, void* d_ws, size_t ws_size,
                              hipStream_t stream) {
  (void)in_sizes; (void)n_in; (void)out_size; (void)ws_size;
  const float* zq   = (const float*)d_in[0];
  const float* zs   = (const float*)d_in[1];
  const float* zv   = (const float*)d_in[2];
  const float* conf = (const float*)d_in[3];
  const float* Wk   = (const float*)d_in[4];
  const float* Wv   = (const float*)d_in[5];
  const float* Wo   = (const float*)d_in[6];
  const float* mem  = (const float*)d_in[7];

  float* vret = (float*)d_out;                      // (B, D)
  float* newmem = vret + (long long)B_DIM * D_DIM;  // (H, D, D)

  float* count = (float*)d_ws;
  float* Pf = (float*)((char*)d_ws + 256);          // 512x512 f32
  float* Sf = (float*)((char*)d_ws + 1048832);      // 512x512 f32
  float* Uf = (float*)((char*)d_ws + 2097408);      // 16x512x512 f32 (split-K G5 out)
  u16* bb   = (u16*)((char*)d_ws + 18874624);
  u16* zsT   = bb;              // 512 x 4096
  u16* zvlT  = bb + 2097152;    // 512 x 4096 (lam-scaled)
  u16* WkT   = bb + 4194304;    // 8192 x 512
  u16* WvT   = bb + 8388608;    // 8192 x 512
  u16* memT  = bb + 12582912;   // 512 x 8192
  u16* WoT   = bb + 16777216;   // 512 x 512
  u16* QT    = bb + 17039360;   // 512 x 512 (Q^T, /16 folded)
  u16* Wk_bf = bb + 17301504;   // 512 x 8192 row-major (dual-output of Wk transpose)

  // D1: 64x64 transposes (Wk dual-output) + zero(Pf,Sf,Uf) + count
  TJobs T;
  T.j[0] = {zs,  zsT,  nullptr, nullptr, 4096, 512,  8,   0,    0};
  T.j[1] = {zv,  zvlT, nullptr, conf,    4096, 512,  8,   512,  1};
  T.j[2] = {Wk,  WkT,  Wk_bf,   nullptr, 512,  8192, 128, 1024, 0};
  T.j[3] = {Wv,  WvT,  nullptr, nullptr, 512,  8192, 128, 2048, 0};
  T.j[4] = {mem, memT, nullptr, nullptr, 8192, 512,  8,   3072, 0};
  T.j[5] = {Wo,  WoT,  nullptr, nullptr, 512,  512,  8,   4096, 0};
  T.j[6] = {nullptr, Pf, nullptr, nullptr, 0, 0, 0,      4160, 3};  // 64 blocks
  T.j[7] = {nullptr, Sf, nullptr, nullptr, 0, 0, 0,      4224, 3};  // 64 blocks
  T.j[8] = {nullptr, Uf, nullptr, nullptr, 0, 0, 0,      4288, 3};  // 1024 blocks
  T.j[9] = {conf, nullptr, nullptr, nullptr, 0, 0, 0,    5312, 2};  // 1 block
  mega_prep<<<5313, 256, 0, stream>>>(T, count);

  // D2: G1 (Pf = Wk @ M, K=8192, split-K 32) + G4 (Sf = zsT @ zvlT^T, K=4096, split-K 16)
  GJobs D2;
  D2.j[0] = {Wk_bf, memT, Pf, nullptr, nullptr,
             8192, 8192, 512, 0, 0, 0, 0,
             1.0f, 8192, 256, 4, 4, 0, 1, 0, 0, 0, 512};
  D2.j[1] = {zsT, zvlT, Sf, nullptr, nullptr,
             4096, 4096, 512, 0, 0, 0, 0,
             1.0f, 4096, 256, 4, 4, 0, 1, 0, 0, 0, 256};
  gemm128<<<768, 256, 0, stream>>>(D2);

  // D3: G5 (Uf_h += WvT_h @ Sf^T, batched 16, split-K 2) + G2 (QT = WoT @ Pf^T, /16)
  GJobs D3;
  D3.j[0] = {WvT, Sf, Uf, nullptr, nullptr,
             512, 512, 512, 262144, 0, 262144, 0,
             1.0f, 512, 256, 4, 4, 1, 2, 0, 0, 1, 512};
  D3.j[1] = {WoT, Pf, QT, nullptr, nullptr,
             512, 512, 512, 0, 0, 0, 0,
             1.0f / 16.0f, 512, 512, 4, 4, 0, 1, 1, 0, 1, 16};
  gemm128<<<528, 256, 0, stream>>>(D3);

  // D4: G6 (newmem = mem + WkT_h @ Uf_h^T / count, batched 16) + G3 (vret = zq @ QT^T)
  GJobs D4;
  D4.j[0] = {WkT, Uf, newmem, mem, count,
             512, 512, 512, 262144, 262144, 262144, 262144,
             1.0f, 512, 512, 4, 4, 1, 1, 3, 0, 1, 256};
  D4.j[1] = {zq, QT, vret, nullptr, nullptr,
             512, 512, 512, 0, 0, 0, 0,
             1.0f, 512, 512, 32, 4, 0, 1, 2, 1, 0, 128};
  gemm128<<<384, 256, 0, stream>>>(D4);
}

// Round 5
// 208.015 us; speedup vs baseline: 1.3186x; 1.3186x over previous
//
#include <hip/hip_runtime.h>

typedef unsigned short u16;
typedef __attribute__((ext_vector_type(8))) short bf16x8;
typedef __attribute__((ext_vector_type(8))) unsigned short u16x8;
typedef __attribute__((ext_vector_type(4))) float f32x4;

#define B_DIM 4096
#define D_DIM 512
#define H_DIM 16

typedef const __attribute__((address_space(1))) unsigned int* gas_t;
typedef __attribute__((address_space(3))) unsigned int* las_t;

__device__ __forceinline__ u16 f2bf(float f) {
  union { float f; unsigned u; } x;
  x.f = f;
  unsigned r = x.u + 0x7FFFu + ((x.u >> 16) & 1u);
  return (u16)(r >> 16);
}

__device__ __forceinline__ float bf2f(u16 h) {
  union { unsigned u; float f; } x;
  x.u = ((unsigned)h) << 16;
  return x.f;
}

__device__ __forceinline__ uint4 pack8(float4 v0, float4 v1) {
  union { uint4 q; u16 h[8]; } u;
  u.h[0] = f2bf(v0.x); u.h[1] = f2bf(v0.y); u.h[2] = f2bf(v0.z); u.h[3] = f2bf(v0.w);
  u.h[4] = f2bf(v1.x); u.h[5] = f2bf(v1.y); u.h[6] = f2bf(v1.z); u.h[7] = f2bf(v1.w);
  return u.q;
}

// ---- prep uber kernel ----
// kind 0: 64x64 LDS transpose f32->bf16 (optional out2 = row-major bf16 copy);
// kind 1: transpose with lam(conf) row-scale;
// kind 2: count reduction (1 block);
// kind 3: hsum — out[r,c] = sum_s in[r*cols + s*512 + c], bf16 in/out,
//         rows = nsum, cols = input row stride; 4 output rows / block.
struct TJob {
  const float* in;
  void* out;
  void* out2;
  const float* conf;
  int rows, cols, tiles_x, tile_off, kind;
};
struct TJobs { TJob j[8]; };

__global__ __launch_bounds__(256) void mega_prep(TJobs J, float* __restrict__ countp) {
  __shared__ float tile[64][65];
  __shared__ float wsum[4];
  const int tid = threadIdx.x;
  int b = blockIdx.x;
  int sel = 0;
#pragma unroll
  for (int i = 1; i < 8; ++i)
    if (b >= J.j[i].tile_off) sel = i;
  TJob jb = J.j[sel];
  b -= jb.tile_off;

  if (jb.kind == 3) {  // hsum of k-stacked bf16 partials
    const u16* src = (const u16*)jb.in;
    u16* dst = (u16*)jb.out;
    const int nsum = jb.rows;
    const long long incols = jb.cols;
    const long long r = (long long)b * 4 + (tid >> 6);
    const int c = (tid & 63) * 8;
    float acc[8] = {0.f, 0.f, 0.f, 0.f, 0.f, 0.f, 0.f, 0.f};
    for (int s = 0; s < nsum; ++s) {
      u16x8 v = *(const u16x8*)(src + r * incols + s * 512 + c);
#pragma unroll
      for (int i = 0; i < 8; ++i) acc[i] += bf2f(v[i]);
    }
    union { uint4 q; u16 h[8]; } o;
#pragma unroll
    for (int i = 0; i < 8; ++i) o.h[i] = f2bf(acc[i]);
    *(uint4*)(dst + r * 512 + c) = o.q;
    return;
  }
  if (jb.kind == 2) {  // count
    float m = 0.f;
    for (int i = tid; i < B_DIM; i += 256) {
      float l = 1.0f - jb.in[i];
      l = fminf(fmaxf(l, 0.f), 1.f);
      m += (l > 0.3f) ? 1.f : 0.f;
    }
    for (int off = 32; off; off >>= 1) m += __shfl_down(m, off, 64);
    if ((tid & 63) == 0) wsum[tid >> 6] = m;
    __syncthreads();
    if (tid == 0) countp[0] = wsum[0] + wsum[1] + wsum[2] + wsum[3];
    return;
  }

  // transpose kinds 0/1: 64x64 tile via LDS.
  // read: float4/lane coalesced rows; write: 32 B/lane contiguous u16 rows.
  const long long c0 = (long long)(b % jb.tiles_x) * 64;
  const long long r0 = (long long)(b / jb.tiles_x) * 64;
  const int rr = tid >> 4;         // 0..15
  const int cc4 = (tid & 15) * 4;  // 0..60
#pragma unroll
  for (int i = 0; i < 4; ++i) {
    int row = i * 16 + rr;
    float4 v = *(const float4*)(jb.in + (r0 + row) * jb.cols + c0 + cc4);
    if (jb.kind == 1) {
      float l = 1.0f - jb.conf[r0 + row];
      l = fminf(fmaxf(l, 0.f), 1.f);
      float s = (l > 0.3f) ? l : 0.f;
      v.x *= s; v.y *= s; v.z *= s; v.w *= s;
    }
    tile[row][cc4] = v.x; tile[row][cc4 + 1] = v.y;
    tile[row][cc4 + 2] = v.z; tile[row][cc4 + 3] = v.w;
    if (jb.out2) {  // row-major bf16 side copy (Wk: saves a second 16 MB pass)
      union { uint2 u; u16 h[4]; } p;
      p.h[0] = f2bf(v.x); p.h[1] = f2bf(v.y); p.h[2] = f2bf(v.z); p.h[3] = f2bf(v.w);
      *(uint2*)((u16*)jb.out2 + (r0 + row) * jb.cols + c0 + cc4) = p.u;
    }
  }
  __syncthreads();
  const int orow = tid >> 2;  // 0..63  (output row = input column)
  const int seg = tid & 3;    // 16 u16 per thread
  union { uint4 q[2]; u16 h[16]; } o;
#pragma unroll
  for (int i = 0; i < 16; ++i) o.h[i] = f2bf(tile[seg * 16 + i][orow]);
  u16* outp = (u16*)jb.out + (c0 + orow) * jb.rows + r0 + seg * 16;
  *(uint4*)outp = o.q[0];
  *(uint4*)(outp + 8) = o.q[1];
}

// ---- 128x128-tile GEMM, BK=64, double-buffered, swizzled LDS ----
// C(M,N) = alpha * A(M,K) @ Bt(N,K)^T, both k-contiguous. 4 waves, each 64x64.
// bf16 operands via global_load_lds(16B); f32 (aflag/bflag) via float4+pack+ds_write.
// LDS chunk swizzle: LDS[row][cl] holds G[row][cl ^ (row&7)] (chunks of 8 elems).
// Split-K (non-batched): bz = k-chunk index; output column-block offset
// coff = bz*sc_b gives atomic-free k-stacked partial stores (reduced later).
// mode 1: store bf16*alpha; 2: store f32*alpha; 3: store f32 = addsrc + acc/(cnt+1e-6).
struct GJob {
  const void* A; const void* Bp; void* C;
  const float* addsrc; const float* cnt;
  long long lda, ldb, ldc, sa_b, sb_b, sc_b, sadd_b;
  float alpha;
  int K, k_chunk, tm, tn, batched, mode, aflag, bflag, nblocks;
};
struct GJobs { GJob j[2]; };

__global__ __launch_bounds__(256, 2) void gemm128(GJobs JJ) {
  __shared__ alignas(16) u16 As[2][128 * 64];
  __shared__ alignas(16) u16 Bs[2][128 * 64];

  int b = blockIdx.x;
  GJob J = JJ.j[0];
  if (b >= J.nblocks) { b -= J.nblocks; J = JJ.j[1]; }

  const int tilesper = J.tm * J.tn;
  const int bz = b / tilesper;
  const int rel = b % tilesper;
  const long long m0 = (long long)(rel / J.tn) * 128;
  const long long n0 = (long long)(rel % J.tn) * 128;

  long long aoff = 0, boff = 0, coff = 0, doff = 0, k0 = 0;
  int Kl = J.K;
  if (J.batched) {
    aoff = (long long)bz * J.sa_b;
    boff = (long long)bz * J.sb_b;
    coff = (long long)bz * J.sc_b;
    doff = (long long)bz * J.sadd_b;
  } else {
    k0 = (long long)bz * J.k_chunk;
    Kl = J.k_chunk;
    coff = (long long)bz * J.sc_b;  // k-stacked partial output (no atomics)
  }

  const int tid = threadIdx.x;
  const int lane = tid & 63, wave = tid >> 6;
  const int wm = (wave & 1) * 64, wn = (wave >> 1) * 64;
  const int fm = lane & 15, fg = lane >> 4;

  auto stage = [&](u16* dst, const void* src, long long ld, long long off,
                   long long rbase, long long t, int isf32) {
    if (!isf32) {
      const u16* gb = (const u16*)src + off;
#pragma unroll
      for (int j = 0; j < 4; ++j) {
        int cc = wave * 4 + j;
        int row = cc * 8 + (lane >> 3);
        int cg = (lane & 7) ^ (row & 7);
        const u16* g = gb + (rbase + row) * ld + t + cg * 8;
        __builtin_amdgcn_global_load_lds((gas_t)(const void*)g,
                                         (las_t)(void*)(dst + cc * 512 + lane * 8),
                                         16, 0, 0);
      }
    } else {
      const float* gb = (const float*)src + off;
#pragma unroll
      for (int p = 0; p < 4; ++p) {
        int idx = p * 256 + tid;
        int row = idx >> 3, cg = idx & 7;
        const float* g = gb + (rbase + row) * ld + t + cg * 8;
        float4 v0 = *(const float4*)g;
        float4 v1 = *(const float4*)(g + 4);
        *(uint4*)&dst[row * 64 + ((cg ^ (row & 7)) * 8)] = pack8(v0, v1);
      }
    }
  };

  f32x4 acc[4][4];
#pragma unroll
  for (int i = 0; i < 4; ++i)
#pragma unroll
    for (int j = 0; j < 4; ++j) acc[i][j] = (f32x4){0.f, 0.f, 0.f, 0.f};

  const int nIter = Kl >> 6;
  stage(As[0], J.A, J.lda, aoff, m0, k0, J.aflag);
  stage(Bs[0], J.Bp, J.ldb, boff, n0, k0, J.bflag);

  for (int i = 0; i < nIter; ++i) {
    __syncthreads();  // drains current buffer's loads
    if (i + 1 < nIter) {
      long long t = k0 + (long long)(i + 1) * 64;
      stage(As[(i + 1) & 1], J.A, J.lda, aoff, m0, t, J.aflag);
      stage(Bs[(i + 1) & 1], J.Bp, J.ldb, boff, n0, t, J.bflag);
    }
    const u16* Ab = As[i & 1];
    const u16* Bb = Bs[i & 1];
#pragma unroll
    for (int kcc = 0; kcc < 8; kcc += 4) {
      bf16x8 af[4], bfr[4];
#pragma unroll
      for (int fi = 0; fi < 4; ++fi) {
        int row = wm + fi * 16 + fm;
        af[fi] = *(const bf16x8*)&Ab[row * 64 + (((kcc + fg) ^ (row & 7)) * 8)];
      }
#pragma unroll
      for (int fj = 0; fj < 4; ++fj) {
        int row = wn + fj * 16 + fm;
        bfr[fj] = *(const bf16x8*)&Bb[row * 64 + (((kcc + fg) ^ (row & 7)) * 8)];
      }
#pragma unroll
      for (int fi = 0; fi < 4; ++fi)
#pragma unroll
        for (int fj = 0; fj < 4; ++fj)
          acc[fi][fj] = __builtin_amdgcn_mfma_f32_16x16x32_bf16(af[fi], bfr[fj], acc[fi][fj], 0, 0, 0);
    }
  }

  float inv = (J.mode == 3) ? 1.0f / (*J.cnt + 1e-6f) : 0.0f;
#pragma unroll
  for (int fi = 0; fi < 4; ++fi) {
#pragma unroll
    for (int r = 0; r < 4; ++r) {
      long long row = m0 + wm + fi * 16 + fg * 4 + r;
#pragma unroll
      for (int fj = 0; fj < 4; ++fj) {
        long long col = n0 + wn + fj * 16 + fm;
        long long idx = row * J.ldc + col;
        float v = acc[fi][fj][r];
        if (J.mode == 1) {
          ((u16*)J.C)[coff + idx] = f2bf(v * J.alpha);
        } else if (J.mode == 2) {
          ((float*)J.C)[coff + idx] = v * J.alpha;
        } else {
          ((float*)J.C)[coff + idx] = J.addsrc[doff + idx] + v * inv;
        }
      }
    }
  }
}

extern "C" void kernel_launch(void* const* d_in, const int* in_sizes, int n_in,
                              void* d_out, int out_size, void* d_ws, size_t ws_size,
                              hipStream_t stream) {
  (void)in_sizes; (void)n_in; (void)out_size; (void)ws_size;
  const float* zq   = (const float*)d_in[0];
  const float* zs   = (const float*)d_in[1];
  const float* zv   = (const float*)d_in[2];
  const float* conf = (const float*)d_in[3];
  const float* Wk   = (const float*)d_in[4];
  const float* Wv   = (const float*)d_in[5];
  const float* Wo   = (const float*)d_in[6];
  const float* mem  = (const float*)d_in[7];

  float* vret = (float*)d_out;                      // (B, D)
  float* newmem = vret + (long long)B_DIM * D_DIM;  // (H, D, D)

  float* count = (float*)d_ws;
  u16* bb = (u16*)((char*)d_ws + 256);
  u16* zsT   = bb;              // 512 x 4096
  u16* zvlT  = bb + 2097152;    // 512 x 4096 (lam-scaled)
  u16* WkT   = bb + 4194304;    // 8192 x 512
  u16* WvT   = bb + 8388608;    // 8192 x 512
  u16* memT  = bb + 12582912;   // 512 x 8192
  u16* WoT   = bb + 16777216;   // 512 x 512
  u16* Wk_bf = bb + 17039360;   // 512 x 8192 row-major (dual-output of Wk transpose)
  u16* Pstk  = bb + 21233664;   // 512 x 8192: [d', h*512+e] = P_h[d',e] partials
  u16* Sstk  = bb + 25427968;   // 512 x 4096: [d1, p*512+d2] = S_p partials
  u16* Pred  = bb + 27525120;   // 512 x 512  = sum_h P_h
  u16* Sred  = bb + 27787264;   // 512 x 512  = sum_p S_p
  u16* QT    = bb + 28049408;   // 512 x 512 (Q^T, /16 folded)
  u16* UT    = bb + 28311552;   // 16 x 512 x 512 (U_h^T)

  // D1: 64x64 transposes (Wk dual-output) + count. No zero jobs (no atomics).
  TJobs T;
  T.j[0] = {zs,  zsT,  nullptr, nullptr, 4096, 512,  8,   0,    0};
  T.j[1] = {zv,  zvlT, nullptr, conf,    4096, 512,  8,   512,  1};
  T.j[2] = {Wk,  WkT,  Wk_bf,   nullptr, 512,  8192, 128, 1024, 0};
  T.j[3] = {Wv,  WvT,  nullptr, nullptr, 512,  8192, 128, 2048, 0};
  T.j[4] = {mem, memT, nullptr, nullptr, 8192, 512,  8,   3072, 0};
  T.j[5] = {Wo,  WoT,  nullptr, nullptr, 512,  512,  8,   4096, 0};
  T.j[6] = {conf, nullptr, nullptr, nullptr, 0, 0, 0,     4160, 2};  // 1 block
  T.j[7] = {nullptr, nullptr, nullptr, nullptr, 0, 0, 0, 1 << 30, 0};
  mega_prep<<<4161, 256, 0, stream>>>(T, count);

  // D2: G1 (Pstk_h = Wk_bf @ memT per k-chunk h, K=8192 split-16, bf16 stores)
  //   + G4 (Sstk_p = zsT @ zvlT^T per k-chunk p, K=4096 split-8, bf16 stores)
  GJobs D2;
  D2.j[0] = {Wk_bf, memT, Pstk, nullptr, nullptr,
             8192, 8192, 8192, 0, 0, 512, 0,
             1.0f, 8192, 512, 4, 4, 0, 1, 0, 0, 256};
  D2.j[1] = {zsT, zvlT, Sstk, nullptr, nullptr,
             4096, 4096, 4096, 0, 0, 512, 0,
             1.0f, 4096, 512, 4, 4, 0, 1, 0, 0, 128};
  gemm128<<<384, 256, 0, stream>>>(D2);

  // D2.5: hsum reductions Pstk->Pred (16 slices), Sstk->Sred (8 slices)
  TJobs R;
  R.j[0] = {(const float*)Pstk, Pred, nullptr, nullptr, 16, 8192, 0, 0,   3};
  R.j[1] = {(const float*)Sstk, Sred, nullptr, nullptr, 8,  4096, 0, 128, 3};
  R.j[2] = {nullptr, nullptr, nullptr, nullptr, 0, 0, 0, 1 << 30, 0};
  R.j[3] = {nullptr, nullptr, nullptr, nullptr, 0, 0, 0, 1 << 30, 0};
  R.j[4] = {nullptr, nullptr, nullptr, nullptr, 0, 0, 0, 1 << 30, 0};
  R.j[5] = {nullptr, nullptr, nullptr, nullptr, 0, 0, 0, 1 << 30, 0};
  R.j[6] = {nullptr, nullptr, nullptr, nullptr, 0, 0, 0, 1 << 30, 0};
  R.j[7] = {nullptr, nullptr, nullptr, nullptr, 0, 0, 0, 1 << 30, 0};
  mega_prep<<<256, 256, 0, stream>>>(R, count);

  // D3: G5 (UT_h = WvT_h @ Sred^T, batched 16) + G2 (QT = WoT @ Pred^T, /16)
  GJobs D3;
  D3.j[0] = {WvT, Sred, UT, nullptr, nullptr,
             512, 512, 512, 262144, 0, 262144, 0,
             1.0f, 512, 512, 4, 4, 1, 1, 0, 0, 256};
  D3.j[1] = {WoT, Pred, QT, nullptr, nullptr,
             512, 512, 512, 0, 0, 0, 0,
             1.0f / 16.0f, 512, 512, 4, 4, 0, 1, 0, 0, 16};
  gemm128<<<272, 256, 0, stream>>>(D3);

  // D4: G6 (newmem = mem + WkT_h @ UT_h^T / count, batched 16) + G3 (vret = zq @ QT^T)
  GJobs D4;
  D4.j[0] = {WkT, UT, newmem, mem, count,
             512, 512, 512, 262144, 262144, 262144, 262144,
             1.0f, 512, 512, 4, 4, 1, 3, 0, 0, 256};
  D4.j[1] = {zq, QT, vret, nullptr, nullptr,
             512, 512, 512, 0, 0, 0, 0,
             1.0f, 512, 512, 32, 4, 0, 2, 1, 0, 128};
  gemm128<<<384, 256, 0, stream>>>(D4);
}

// Round 6
// 201.553 us; speedup vs baseline: 1.3609x; 1.0321x over previous
//
#include <hip/hip_runtime.h>

typedef unsigned short u16;
typedef __attribute__((ext_vector_type(8))) short bf16x8;
typedef __attribute__((ext_vector_type(8))) unsigned short u16x8;
typedef __attribute__((ext_vector_type(4))) float f32x4;

#define B_DIM 4096
#define D_DIM 512
#define H_DIM 16

typedef const __attribute__((address_space(1))) unsigned int* gas_t;
typedef __attribute__((address_space(3))) unsigned int* las_t;

__device__ __forceinline__ u16 f2bf(float f) {
  union { float f; unsigned u; } x;
  x.f = f;
  unsigned r = x.u + 0x7FFFu + ((x.u >> 16) & 1u);
  return (u16)(r >> 16);
}

__device__ __forceinline__ float bf2f(u16 h) {
  union { unsigned u; float f; } x;
  x.u = ((unsigned)h) << 16;
  return x.f;
}

__device__ __forceinline__ uint4 pack8(float4 v0, float4 v1) {
  union { uint4 q; u16 h[8]; } u;
  u.h[0] = f2bf(v0.x); u.h[1] = f2bf(v0.y); u.h[2] = f2bf(v0.z); u.h[3] = f2bf(v0.w);
  u.h[4] = f2bf(v1.x); u.h[5] = f2bf(v1.y); u.h[6] = f2bf(v1.z); u.h[7] = f2bf(v1.w);
  return u.q;
}

// ---- prep uber kernel ----
// kind 0: 64x64 LDS transpose f32->bf16 (optional out2 = row-major bf16 copy);
// kind 1: transpose with lam(conf) row-scale;
// kind 2: count reduction (1 block);
// kind 3: hsum — out[r,c] = sum_s in[r*cols + s*512 + c], bf16 in/out,
//         rows = nsum, cols = input row stride; 4 output rows / block.
struct TJob {
  const float* in;
  void* out;
  void* out2;
  const float* conf;
  int rows, cols, tiles_x, tile_off, kind;
};
struct TJobs { TJob j[8]; };

__global__ __launch_bounds__(256) void mega_prep(TJobs J, float* __restrict__ countp) {
  __shared__ float tile[64][65];
  __shared__ float wsum[4];
  const int tid = threadIdx.x;
  int b = blockIdx.x;
  int sel = 0;
#pragma unroll
  for (int i = 1; i < 8; ++i)
    if (b >= J.j[i].tile_off) sel = i;
  TJob jb = J.j[sel];
  b -= jb.tile_off;

  if (jb.kind == 3) {  // hsum of k-stacked bf16 partials
    const u16* src = (const u16*)jb.in;
    u16* dst = (u16*)jb.out;
    const int nsum = jb.rows;
    const long long incols = jb.cols;
    const long long r = (long long)b * 4 + (tid >> 6);
    const int c = (tid & 63) * 8;
    float acc[8] = {0.f, 0.f, 0.f, 0.f, 0.f, 0.f, 0.f, 0.f};
#pragma unroll 4
    for (int s = 0; s < nsum; ++s) {
      u16x8 v = *(const u16x8*)(src + r * incols + s * 512 + c);
#pragma unroll
      for (int i = 0; i < 8; ++i) acc[i] += bf2f(v[i]);
    }
    union { uint4 q; u16 h[8]; } o;
#pragma unroll
    for (int i = 0; i < 8; ++i) o.h[i] = f2bf(acc[i]);
    *(uint4*)(dst + r * 512 + c) = o.q;
    return;
  }
  if (jb.kind == 2) {  // count
    float m = 0.f;
    for (int i = tid; i < B_DIM; i += 256) {
      float l = 1.0f - jb.in[i];
      l = fminf(fmaxf(l, 0.f), 1.f);
      m += (l > 0.3f) ? 1.f : 0.f;
    }
    for (int off = 32; off; off >>= 1) m += __shfl_down(m, off, 64);
    if ((tid & 63) == 0) wsum[tid >> 6] = m;
    __syncthreads();
    if (tid == 0) countp[0] = wsum[0] + wsum[1] + wsum[2] + wsum[3];
    return;
  }

  // transpose kinds 0/1: 64x64 tile via LDS.
  // read: float4/lane coalesced rows; write: 32 B/lane contiguous u16 rows.
  const long long c0 = (long long)(b % jb.tiles_x) * 64;
  const long long r0 = (long long)(b / jb.tiles_x) * 64;
  const int rr = tid >> 4;         // 0..15
  const int cc4 = (tid & 15) * 4;  // 0..60
#pragma unroll
  for (int i = 0; i < 4; ++i) {
    int row = i * 16 + rr;
    float4 v = *(const float4*)(jb.in + (r0 + row) * jb.cols + c0 + cc4);
    if (jb.kind == 1) {
      float l = 1.0f - jb.conf[r0 + row];
      l = fminf(fmaxf(l, 0.f), 1.f);
      float s = (l > 0.3f) ? l : 0.f;
      v.x *= s; v.y *= s; v.z *= s; v.w *= s;
    }
    tile[row][cc4] = v.x; tile[row][cc4 + 1] = v.y;
    tile[row][cc4 + 2] = v.z; tile[row][cc4 + 3] = v.w;
    if (jb.out2) {  // row-major bf16 side copy (Wk: saves a second 16 MB pass)
      union { uint2 u; u16 h[4]; } p;
      p.h[0] = f2bf(v.x); p.h[1] = f2bf(v.y); p.h[2] = f2bf(v.z); p.h[3] = f2bf(v.w);
      *(uint2*)((u16*)jb.out2 + (r0 + row) * jb.cols + c0 + cc4) = p.u;
    }
  }
  __syncthreads();
  const int orow = tid >> 2;  // 0..63  (output row = input column)
  const int seg = tid & 3;    // 16 u16 per thread
  union { uint4 q[2]; u16 h[16]; } o;
#pragma unroll
  for (int i = 0; i < 16; ++i) o.h[i] = f2bf(tile[seg * 16 + i][orow]);
  u16* outp = (u16*)jb.out + (c0 + orow) * jb.rows + r0 + seg * 16;
  *(uint4*)outp = o.q[0];
  *(uint4*)(outp + 8) = o.q[1];
}

// ---- 128x128-tile GEMM, BK=64, double-buffered, swizzled LDS ----
// C(M,N) = alpha * A(M,K) @ Bt(N,K)^T, both k-contiguous. 4 waves, each 64x64.
// bf16 operands via global_load_lds(16B); f32 (aflag/bflag) via float4+pack+ds_write.
// LDS chunk swizzle: LDS[row][cl] holds G[row][cl ^ (row&7)] (chunks of 8 elems).
// XCD-aware bijective blockIdx swizzle (m204): consecutive LOGICAL blocks (same
// k-chunk / shared operand panels) land on the same XCD for L2 reuse.
// Split-K (non-batched): bz = k-chunk index; output column-block offset
// coff = bz*sc_b gives atomic-free k-stacked partial stores (reduced later).
// mode 1: store bf16*alpha; 2: store f32*alpha; 3: store f32 = addsrc + acc/(cnt+1e-6).
struct GJob {
  const void* A; const void* Bp; void* C;
  const float* addsrc; const float* cnt;
  long long lda, ldb, ldc, sa_b, sb_b, sc_b, sadd_b;
  float alpha;
  int K, k_chunk, tm, tn, batched, mode, aflag, bflag, nblocks;
};
struct GJobs { GJob j[2]; };

__global__ __launch_bounds__(256, 2) void gemm128(GJobs JJ) {
  __shared__ alignas(16) u16 As[2][128 * 64];
  __shared__ alignas(16) u16 Bs[2][128 * 64];

  // XCD-aware bijective swizzle: hardware round-robins blockIdx across 8 XCDs;
  // map so that each XCD owns a contiguous run of logical block IDs.
  const int nwg = gridDim.x;
  const int orig = blockIdx.x;
  const int q = nwg >> 3, r = nwg & 7;
  const int xcd = orig & 7;
  const int loc = orig >> 3;
  int b = (xcd < r ? xcd * (q + 1) : r * (q + 1) + (xcd - r) * q) + loc;

  GJob J = JJ.j[0];
  if (b >= J.nblocks) { b -= J.nblocks; J = JJ.j[1]; }

  const int tilesper = J.tm * J.tn;
  const int bz = b / tilesper;
  const int rel = b % tilesper;
  const long long m0 = (long long)(rel / J.tn) * 128;
  const long long n0 = (long long)(rel % J.tn) * 128;

  long long aoff = 0, boff = 0, coff = 0, doff = 0, k0 = 0;
  int Kl = J.K;
  if (J.batched) {
    aoff = (long long)bz * J.sa_b;
    boff = (long long)bz * J.sb_b;
    coff = (long long)bz * J.sc_b;
    doff = (long long)bz * J.sadd_b;
  } else {
    k0 = (long long)bz * J.k_chunk;
    Kl = J.k_chunk;
    coff = (long long)bz * J.sc_b;  // k-stacked partial output (no atomics)
  }

  const int tid = threadIdx.x;
  const int lane = tid & 63, wave = tid >> 6;
  const int wm = (wave & 1) * 64, wn = (wave >> 1) * 64;
  const int fm = lane & 15, fg = lane >> 4;

  auto stage = [&](u16* dst, const void* src, long long ld, long long off,
                   long long rbase, long long t, int isf32) {
    if (!isf32) {
      const u16* gb = (const u16*)src + off;
#pragma unroll
      for (int j = 0; j < 4; ++j) {
        int cc = wave * 4 + j;
        int row = cc * 8 + (lane >> 3);
        int cg = (lane & 7) ^ (row & 7);
        const u16* g = gb + (rbase + row) * ld + t + cg * 8;
        __builtin_amdgcn_global_load_lds((gas_t)(const void*)g,
                                         (las_t)(void*)(dst + cc * 512 + lane * 8),
                                         16, 0, 0);
      }
    } else {
      const float* gb = (const float*)src + off;
#pragma unroll
      for (int p = 0; p < 4; ++p) {
        int idx = p * 256 + tid;
        int row = idx >> 3, cg = idx & 7;
        const float* g = gb + (rbase + row) * ld + t + cg * 8;
        float4 v0 = *(const float4*)g;
        float4 v1 = *(const float4*)(g + 4);
        *(uint4*)&dst[row * 64 + ((cg ^ (row & 7)) * 8)] = pack8(v0, v1);
      }
    }
  };

  f32x4 acc[4][4];
#pragma unroll
  for (int i = 0; i < 4; ++i)
#pragma unroll
    for (int j = 0; j < 4; ++j) acc[i][j] = (f32x4){0.f, 0.f, 0.f, 0.f};

  const int nIter = Kl >> 6;
  stage(As[0], J.A, J.lda, aoff, m0, k0, J.aflag);
  stage(Bs[0], J.Bp, J.ldb, boff, n0, k0, J.bflag);

  for (int i = 0; i < nIter; ++i) {
    __syncthreads();  // drains current buffer's loads
    if (i + 1 < nIter) {
      long long t = k0 + (long long)(i + 1) * 64;
      stage(As[(i + 1) & 1], J.A, J.lda, aoff, m0, t, J.aflag);
      stage(Bs[(i + 1) & 1], J.Bp, J.ldb, boff, n0, t, J.bflag);
    }
    const u16* Ab = As[i & 1];
    const u16* Bb = Bs[i & 1];
#pragma unroll
    for (int kcc = 0; kcc < 8; kcc += 4) {
      bf16x8 af[4], bfr[4];
#pragma unroll
      for (int fi = 0; fi < 4; ++fi) {
        int row = wm + fi * 16 + fm;
        af[fi] = *(const bf16x8*)&Ab[row * 64 + (((kcc + fg) ^ (row & 7)) * 8)];
      }
#pragma unroll
      for (int fj = 0; fj < 4; ++fj) {
        int row = wn + fj * 16 + fm;
        bfr[fj] = *(const bf16x8*)&Bb[row * 64 + (((kcc + fg) ^ (row & 7)) * 8)];
      }
#pragma unroll
      for (int fi = 0; fi < 4; ++fi)
#pragma unroll
        for (int fj = 0; fj < 4; ++fj)
          acc[fi][fj] = __builtin_amdgcn_mfma_f32_16x16x32_bf16(af[fi], bfr[fj], acc[fi][fj], 0, 0, 0);
    }
  }

  float inv = (J.mode == 3) ? 1.0f / (*J.cnt + 1e-6f) : 0.0f;
#pragma unroll
  for (int fi = 0; fi < 4; ++fi) {
#pragma unroll
    for (int r2 = 0; r2 < 4; ++r2) {
      long long row = m0 + wm + fi * 16 + fg * 4 + r2;
#pragma unroll
      for (int fj = 0; fj < 4; ++fj) {
        long long col = n0 + wn + fj * 16 + fm;
        long long idx = row * J.ldc + col;
        float v = acc[fi][fj][r2];
        if (J.mode == 1) {
          ((u16*)J.C)[coff + idx] = f2bf(v * J.alpha);
        } else if (J.mode == 2) {
          ((float*)J.C)[coff + idx] = v * J.alpha;
        } else {
          ((float*)J.C)[coff + idx] = J.addsrc[doff + idx] + v * inv;
        }
      }
    }
  }
}

extern "C" void kernel_launch(void* const* d_in, const int* in_sizes, int n_in,
                              void* d_out, int out_size, void* d_ws, size_t ws_size,
                              hipStream_t stream) {
  (void)in_sizes; (void)n_in; (void)out_size; (void)ws_size;
  const float* zq   = (const float*)d_in[0];
  const float* zs   = (const float*)d_in[1];
  const float* zv   = (const float*)d_in[2];
  const float* conf = (const float*)d_in[3];
  const float* Wk   = (const float*)d_in[4];
  const float* Wv   = (const float*)d_in[5];
  const float* Wo   = (const float*)d_in[6];
  const float* mem  = (const float*)d_in[7];

  float* vret = (float*)d_out;                      // (B, D)
  float* newmem = vret + (long long)B_DIM * D_DIM;  // (H, D, D)

  float* count = (float*)d_ws;
  u16* bb = (u16*)((char*)d_ws + 256);
  u16* zsT   = bb;              // 512 x 4096
  u16* zvlT  = bb + 2097152;    // 512 x 4096 (lam-scaled)
  u16* WkT   = bb + 4194304;    // 8192 x 512
  u16* WvT   = bb + 8388608;    // 8192 x 512
  u16* memT  = bb + 12582912;   // 512 x 8192
  u16* WoT   = bb + 16777216;   // 512 x 512
  u16* Wk_bf = bb + 17039360;   // 512 x 8192 row-major (dual-output of Wk transpose)
  u16* Pstk  = bb + 21233664;   // 512 x 16384: [d', chunk*512+e] partials (32 chunks)
  u16* Sstk  = bb + 29622272;   // 512 x 8192:  [d1, chunk*512+d2] partials (16 chunks)
  u16* Pred  = bb + 33816576;   // 512 x 512  = sum_h P_h
  u16* Sred  = bb + 34078720;   // 512 x 512  = sum_p S_p
  u16* QT    = bb + 34340864;   // 512 x 512 (Q^T, /16 folded)
  u16* UT    = bb + 34603008;   // 16 x 512 x 512 (U_h^T)

  // D1: 64x64 transposes (Wk dual-output) + count. No zero jobs (no atomics).
  TJobs T;
  T.j[0] = {zs,  zsT,  nullptr, nullptr, 4096, 512,  8,   0,    0};
  T.j[1] = {zv,  zvlT, nullptr, conf,    4096, 512,  8,   512,  1};
  T.j[2] = {Wk,  WkT,  Wk_bf,   nullptr, 512,  8192, 128, 1024, 0};
  T.j[3] = {Wv,  WvT,  nullptr, nullptr, 512,  8192, 128, 2048, 0};
  T.j[4] = {mem, memT, nullptr, nullptr, 8192, 512,  8,   3072, 0};
  T.j[5] = {Wo,  WoT,  nullptr, nullptr, 512,  512,  8,   4096, 0};
  T.j[6] = {conf, nullptr, nullptr, nullptr, 0, 0, 0,     4160, 2};  // 1 block
  T.j[7] = {nullptr, nullptr, nullptr, nullptr, 0, 0, 0, 1 << 30, 0};
  mega_prep<<<4161, 256, 0, stream>>>(T, count);

  // D2: G1 (Pstk_c = Wk_bf @ memT per k-chunk, K=8192 split-32, bf16 stores)
  //   + G4 (Sstk_c = zsT @ zvlT^T per k-chunk, K=4096 split-16, bf16 stores)
  // 768 blocks: fills all 512 block-slots (2/CU) + second half-wave.
  GJobs D2;
  D2.j[0] = {Wk_bf, memT, Pstk, nullptr, nullptr,
             8192, 8192, 16384, 0, 0, 512, 0,
             1.0f, 8192, 256, 4, 4, 0, 1, 0, 0, 512};
  D2.j[1] = {zsT, zvlT, Sstk, nullptr, nullptr,
             4096, 4096, 8192, 0, 0, 512, 0,
             1.0f, 4096, 256, 4, 4, 0, 1, 0, 0, 256};
  gemm128<<<768, 256, 0, stream>>>(D2);

  // D2.5: hsum reductions Pstk->Pred (32 slices), Sstk->Sred (16 slices)
  TJobs R;
  R.j[0] = {(const float*)Pstk, Pred, nullptr, nullptr, 32, 16384, 0, 0,   3};
  R.j[1] = {(const float*)Sstk, Sred, nullptr, nullptr, 16, 8192,  0, 128, 3};
  R.j[2] = {nullptr, nullptr, nullptr, nullptr, 0, 0, 0, 1 << 30, 0};
  R.j[3] = {nullptr, nullptr, nullptr, nullptr, 0, 0, 0, 1 << 30, 0};
  R.j[4] = {nullptr, nullptr, nullptr, nullptr, 0, 0, 0, 1 << 30, 0};
  R.j[5] = {nullptr, nullptr, nullptr, nullptr, 0, 0, 0, 1 << 30, 0};
  R.j[6] = {nullptr, nullptr, nullptr, nullptr, 0, 0, 0, 1 << 30, 0};
  R.j[7] = {nullptr, nullptr, nullptr, nullptr, 0, 0, 0, 1 << 30, 0};
  mega_prep<<<256, 256, 0, stream>>>(R, count);

  // D3: G5 (UT_h = WvT_h @ Sred^T, batched 16) + G2 (QT = WoT @ Pred^T, /16)
  GJobs D3;
  D3.j[0] = {WvT, Sred, UT, nullptr, nullptr,
             512, 512, 512, 262144, 0, 262144, 0,
             1.0f, 512, 512, 4, 4, 1, 1, 0, 0, 256};
  D3.j[1] = {WoT, Pred, QT, nullptr, nullptr,
             512, 512, 512, 0, 0, 0, 0,
             1.0f / 16.0f, 512, 512, 4, 4, 0, 1, 0, 0, 16};
  gemm128<<<272, 256, 0, stream>>>(D3);

  // D4: G6 (newmem = mem + WkT_h @ UT_h^T / count, batched 16) + G3 (vret = zq @ QT^T)
  GJobs D4;
  D4.j[0] = {WkT, UT, newmem, mem, count,
             512, 512, 512, 262144, 262144, 262144, 262144,
             1.0f, 512, 512, 4, 4, 1, 3, 0, 0, 256};
  D4.j[1] = {zq, QT, vret, nullptr, nullptr,
             512, 512, 512, 0, 0, 0, 0,
             1.0f, 512, 512, 32, 4, 0, 2, 1, 0, 128};
  gemm128<<<384, 256, 0, stream>>>(D4);
}

// Round 9
// 200.618 us; speedup vs baseline: 1.3672x; 1.0047x over previous
//
#include <hip/hip_runtime.h>

typedef unsigned short u16;
typedef __attribute__((ext_vector_type(8))) short bf16x8;
typedef __attribute__((ext_vector_type(8))) unsigned short u16x8;
typedef __attribute__((ext_vector_type(4))) float f32x4;

#define B_DIM 4096
#define D_DIM 512
#define H_DIM 16

typedef const __attribute__((address_space(1))) unsigned int* gas_t;
typedef __attribute__((address_space(3))) unsigned int* las_t;

__device__ __forceinline__ u16 f2bf(float f) {
  union { float f; unsigned u; } x;
  x.f = f;
  unsigned r = x.u + 0x7FFFu + ((x.u >> 16) & 1u);
  return (u16)(r >> 16);
}

__device__ __forceinline__ float bf2f(u16 h) {
  union { unsigned u; float f; } x;
  x.u = ((unsigned)h) << 16;
  return x.f;
}

__device__ __forceinline__ uint4 pack8(float4 v0, float4 v1) {
  union { uint4 q; u16 h[8]; } u;
  u.h[0] = f2bf(v0.x); u.h[1] = f2bf(v0.y); u.h[2] = f2bf(v0.z); u.h[3] = f2bf(v0.w);
  u.h[4] = f2bf(v1.x); u.h[5] = f2bf(v1.y); u.h[6] = f2bf(v1.z); u.h[7] = f2bf(v1.w);
  return u.q;
}

// ---- prep uber kernel ----
// kind 0: 64x64 LDS transpose f32->bf16 (optional out2 = row-major bf16 copy);
// kind 1: transpose with lam(conf) row-scale;
// kind 2: count reduction (1 block);
// kind 3: hsum — out[r,c] = sum_s in[r*cols + s*512 + c], bf16 in/out,
//         rows = nsum, cols = input row stride; 4 output rows / block.
struct TJob {
  const float* in;
  void* out;
  void* out2;
  const float* conf;
  int rows, cols, tiles_x, tile_off, kind;
};
struct TJobs { TJob j[8]; };

__global__ __launch_bounds__(256) void mega_prep(TJobs J, float* __restrict__ countp) {
  __shared__ float tile[64][65];
  __shared__ float wsum[4];
  const int tid = threadIdx.x;
  int b = blockIdx.x;
  int sel = 0;
#pragma unroll
  for (int i = 1; i < 8; ++i)
    if (b >= J.j[i].tile_off) sel = i;
  TJob jb = J.j[sel];
  b -= jb.tile_off;

  if (jb.kind == 3) {  // hsum of k-stacked bf16 partials
    const u16* src = (const u16*)jb.in;
    u16* dst = (u16*)jb.out;
    const int nsum = jb.rows;
    const long long incols = jb.cols;
    const long long r = (long long)b * 4 + (tid >> 6);
    const int c = (tid & 63) * 8;
    float acc[8] = {0.f, 0.f, 0.f, 0.f, 0.f, 0.f, 0.f, 0.f};
#pragma unroll 4
    for (int s = 0; s < nsum; ++s) {
      u16x8 v = *(const u16x8*)(src + r * incols + s * 512 + c);
#pragma unroll
      for (int i = 0; i < 8; ++i) acc[i] += bf2f(v[i]);
    }
    union { uint4 q; u16 h[8]; } o;
#pragma unroll
    for (int i = 0; i < 8; ++i) o.h[i] = f2bf(acc[i]);
    *(uint4*)(dst + r * 512 + c) = o.q;
    return;
  }
  if (jb.kind == 2) {  // count
    float m = 0.f;
    for (int i = tid; i < B_DIM; i += 256) {
      float l = 1.0f - jb.in[i];
      l = fminf(fmaxf(l, 0.f), 1.f);
      m += (l > 0.3f) ? 1.f : 0.f;
    }
    for (int off = 32; off; off >>= 1) m += __shfl_down(m, off, 64);
    if ((tid & 63) == 0) wsum[tid >> 6] = m;
    __syncthreads();
    if (tid == 0) countp[0] = wsum[0] + wsum[1] + wsum[2] + wsum[3];
    return;
  }

  // transpose kinds 0/1: 64x64 tile via LDS.
  // read: float4/lane coalesced rows; write: 32 B/lane contiguous u16 rows.
  const long long c0 = (long long)(b % jb.tiles_x) * 64;
  const long long r0 = (long long)(b / jb.tiles_x) * 64;
  const int rr = tid >> 4;         // 0..15
  const int cc4 = (tid & 15) * 4;  // 0..60
#pragma unroll
  for (int i = 0; i < 4; ++i) {
    int row = i * 16 + rr;
    float4 v = *(const float4*)(jb.in + (r0 + row) * jb.cols + c0 + cc4);
    if (jb.kind == 1) {
      float l = 1.0f - jb.conf[r0 + row];
      l = fminf(fmaxf(l, 0.f), 1.f);
      float s = (l > 0.3f) ? l : 0.f;
      v.x *= s; v.y *= s; v.z *= s; v.w *= s;
    }
    tile[row][cc4] = v.x; tile[row][cc4 + 1] = v.y;
    tile[row][cc4 + 2] = v.z; tile[row][cc4 + 3] = v.w;
    if (jb.out2) {  // row-major bf16 side copy (Wk: saves a second 16 MB pass)
      union { uint2 u; u16 h[4]; } p;
      p.h[0] = f2bf(v.x); p.h[1] = f2bf(v.y); p.h[2] = f2bf(v.z); p.h[3] = f2bf(v.w);
      *(uint2*)((u16*)jb.out2 + (r0 + row) * jb.cols + c0 + cc4) = p.u;
    }
  }
  __syncthreads();
  const int orow = tid >> 2;  // 0..63  (output row = input column)
  const int seg = tid & 3;    // 16 u16 per thread
  union { uint4 q[2]; u16 h[16]; } o;
#pragma unroll
  for (int i = 0; i < 16; ++i) o.h[i] = f2bf(tile[seg * 16 + i][orow]);
  u16* outp = (u16*)jb.out + (c0 + orow) * jb.rows + r0 + seg * 16;
  *(uint4*)outp = o.q[0];
  *(uint4*)(outp + 8) = o.q[1];
}

// ---- 128x128-tile GEMM, BK=64, double-buffered, swizzled LDS ----
// C(M,N) = alpha * A(M,K) @ Bt(N,K)^T, both k-contiguous. 4 waves, each 64x64.
// bf16 operands via global_load_lds(16B); f32 (aflag/bflag) via float4+pack+ds_write.
// LDS chunk swizzle: LDS[row][cl] holds G[row][cl ^ (row&7)] (chunks of 8 elems).
// XCD-aware bijective blockIdx swizzle (m204): consecutive LOGICAL blocks (same
// k-chunk / shared operand panels) land on the same XCD for L2 reuse.
// Split-K (non-batched): bz = k-chunk index; output column-block offset
// coff = bz*sc_b gives atomic-free k-stacked partial stores (reduced later).
// mode 1: store bf16*alpha; 2: store f32*alpha; 3: store f32 = addsrc + acc/(cnt+1e-6).
struct GJob {
  const void* A; const void* Bp; void* C;
  const float* addsrc; const float* cnt;
  long long lda, ldb, ldc, sa_b, sb_b, sc_b, sadd_b;
  float alpha;
  int K, k_chunk, tm, tn, batched, mode, aflag, bflag, nblocks;
};
struct GJobs { GJob j[2]; };

__global__ __launch_bounds__(256, 2) void gemm128(GJobs JJ) {
  __shared__ alignas(16) u16 As[2][128 * 64];
  __shared__ alignas(16) u16 Bs[2][128 * 64];

  // XCD-aware bijective swizzle: hardware round-robins blockIdx across 8 XCDs;
  // map so that each XCD owns a contiguous run of logical block IDs.
  const int nwg = gridDim.x;
  const int orig = blockIdx.x;
  const int q = nwg >> 3, r = nwg & 7;
  const int xcd = orig & 7;
  const int loc = orig >> 3;
  int b = (xcd < r ? xcd * (q + 1) : r * (q + 1) + (xcd - r) * q) + loc;

  GJob J = JJ.j[0];
  if (b >= J.nblocks) { b -= J.nblocks; J = JJ.j[1]; }

  const int tilesper = J.tm * J.tn;
  const int bz = b / tilesper;
  const int rel = b % tilesper;
  const long long m0 = (long long)(rel / J.tn) * 128;
  const long long n0 = (long long)(rel % J.tn) * 128;

  long long aoff = 0, boff = 0, coff = 0, doff = 0, k0 = 0;
  int Kl = J.K;
  if (J.batched) {
    aoff = (long long)bz * J.sa_b;
    boff = (long long)bz * J.sb_b;
    coff = (long long)bz * J.sc_b;
    doff = (long long)bz * J.sadd_b;
  } else {
    k0 = (long long)bz * J.k_chunk;
    Kl = J.k_chunk;
    coff = (long long)bz * J.sc_b;  // k-stacked partial output (no atomics)
  }

  const int tid = threadIdx.x;
  const int lane = tid & 63, wave = tid >> 6;
  const int wm = (wave & 1) * 64, wn = (wave >> 1) * 64;
  const int fm = lane & 15, fg = lane >> 4;

  auto stage = [&](u16* dst, const void* src, long long ld, long long off,
                   long long rbase, long long t, int isf32) {
    if (!isf32) {
      const u16* gb = (const u16*)src + off;
#pragma unroll
      for (int j = 0; j < 4; ++j) {
        int cc = wave * 4 + j;
        int row = cc * 8 + (lane >> 3);
        int cg = (lane & 7) ^ (row & 7);
        const u16* g = gb + (rbase + row) * ld + t + cg * 8;
        __builtin_amdgcn_global_load_lds((gas_t)(const void*)g,
                                         (las_t)(void*)(dst + cc * 512 + lane * 8),
                                         16, 0, 0);
      }
    } else {
      const float* gb = (const float*)src + off;
#pragma unroll
      for (int p = 0; p < 4; ++p) {
        int idx = p * 256 + tid;
        int row = idx >> 3, cg = idx & 7;
        const float* g = gb + (rbase + row) * ld + t + cg * 8;
        float4 v0 = *(const float4*)g;
        float4 v1 = *(const float4*)(g + 4);
        *(uint4*)&dst[row * 64 + ((cg ^ (row & 7)) * 8)] = pack8(v0, v1);
      }
    }
  };

  f32x4 acc[4][4];
#pragma unroll
  for (int i = 0; i < 4; ++i)
#pragma unroll
    for (int j = 0; j < 4; ++j) acc[i][j] = (f32x4){0.f, 0.f, 0.f, 0.f};

  const int nIter = Kl >> 6;
  stage(As[0], J.A, J.lda, aoff, m0, k0, J.aflag);
  stage(Bs[0], J.Bp, J.ldb, boff, n0, k0, J.bflag);

  for (int i = 0; i < nIter; ++i) {
    __syncthreads();  // drains current buffer's loads
    if (i + 1 < nIter) {
      long long t = k0 + (long long)(i + 1) * 64;
      stage(As[(i + 1) & 1], J.A, J.lda, aoff, m0, t, J.aflag);
      stage(Bs[(i + 1) & 1], J.Bp, J.ldb, boff, n0, t, J.bflag);
    }
    const u16* Ab = As[i & 1];
    const u16* Bb = Bs[i & 1];
#pragma unroll
    for (int kcc = 0; kcc < 8; kcc += 4) {
      bf16x8 af[4], bfr[4];
#pragma unroll
      for (int fi = 0; fi < 4; ++fi) {
        int row = wm + fi * 16 + fm;
        af[fi] = *(const bf16x8*)&Ab[row * 64 + (((kcc + fg) ^ (row & 7)) * 8)];
      }
#pragma unroll
      for (int fj = 0; fj < 4; ++fj) {
        int row = wn + fj * 16 + fm;
        bfr[fj] = *(const bf16x8*)&Bb[row * 64 + (((kcc + fg) ^ (row & 7)) * 8)];
      }
#pragma unroll
      for (int fi = 0; fi < 4; ++fi)
#pragma unroll
        for (int fj = 0; fj < 4; ++fj)
          acc[fi][fj] = __builtin_amdgcn_mfma_f32_16x16x32_bf16(af[fi], bfr[fj], acc[fi][fj], 0, 0, 0);
    }
  }

  float inv = (J.mode == 3) ? 1.0f / (*J.cnt + 1e-6f) : 0.0f;
#pragma unroll
  for (int fi = 0; fi < 4; ++fi) {
#pragma unroll
    for (int r2 = 0; r2 < 4; ++r2) {
      long long row = m0 + wm + fi * 16 + fg * 4 + r2;
#pragma unroll
      for (int fj = 0; fj < 4; ++fj) {
        long long col = n0 + wn + fj * 16 + fm;
        long long idx = row * J.ldc + col;
        float v = acc[fi][fj][r2];
        if (J.mode == 1) {
          ((u16*)J.C)[coff + idx] = f2bf(v * J.alpha);
        } else if (J.mode == 2) {
          ((float*)J.C)[coff + idx] = v * J.alpha;
        } else {
          ((float*)J.C)[coff + idx] = J.addsrc[doff + idx] + v * inv;
        }
      }
    }
  }
}

extern "C" void kernel_launch(void* const* d_in, const int* in_sizes, int n_in,
                              void* d_out, int out_size, void* d_ws, size_t ws_size,
                              hipStream_t stream) {
  (void)in_sizes; (void)n_in; (void)out_size; (void)ws_size;
  const float* zq   = (const float*)d_in[0];
  const float* zs   = (const float*)d_in[1];
  const float* zv   = (const float*)d_in[2];
  const float* conf = (const float*)d_in[3];
  const float* Wk   = (const float*)d_in[4];
  const float* Wv   = (const float*)d_in[5];
  const float* Wo   = (const float*)d_in[6];
  const float* mem  = (const float*)d_in[7];

  float* vret = (float*)d_out;                      // (B, D)
  float* newmem = vret + (long long)B_DIM * D_DIM;  // (H, D, D)

  float* count = (float*)d_ws;
  u16* bb = (u16*)((char*)d_ws + 256);
  u16* zsT   = bb;              // 512 x 4096
  u16* zvlT  = bb + 2097152;    // 512 x 4096 (lam-scaled)
  u16* WkT   = bb + 4194304;    // 8192 x 512
  u16* WvT   = bb + 8388608;    // 8192 x 512
  u16* memT  = bb + 12582912;   // 512 x 8192
  u16* WoT   = bb + 16777216;   // 512 x 512
  u16* Wk_bf = bb + 17039360;   // 512 x 8192 row-major (dual-output of Wk transpose)
  u16* Pstk  = bb + 21233664;   // 512 x 8192: [d', chunk*512+e] partials (16 chunks)
  u16* Sstk  = bb + 25427968;   // 512 x 8192: [d1, chunk*512+d2] partials (16 chunks)
  u16* Pred  = bb + 29622272;   // 512 x 512  = sum_c P_c
  u16* Sred  = bb + 29884416;   // 512 x 512  = sum_c S_c
  u16* QT    = bb + 30146560;   // 512 x 512 (Q^T, /16 folded)
  u16* UT    = bb + 30408704;   // 16 x 512 x 512 (U_h^T)

  // D1: 64x64 transposes (Wk dual-output) + count. No zero jobs (no atomics).
  TJobs T;
  T.j[0] = {zs,  zsT,  nullptr, nullptr, 4096, 512,  8,   0,    0};
  T.j[1] = {zv,  zvlT, nullptr, conf,    4096, 512,  8,   512,  1};
  T.j[2] = {Wk,  WkT,  Wk_bf,   nullptr, 512,  8192, 128, 1024, 0};
  T.j[3] = {Wv,  WvT,  nullptr, nullptr, 512,  8192, 128, 2048, 0};
  T.j[4] = {mem, memT, nullptr, nullptr, 8192, 512,  8,   3072, 0};
  T.j[5] = {Wo,  WoT,  nullptr, nullptr, 512,  512,  8,   4096, 0};
  T.j[6] = {conf, nullptr, nullptr, nullptr, 0, 0, 0,     4160, 2};  // 1 block
  T.j[7] = {nullptr, nullptr, nullptr, nullptr, 0, 0, 0, 1 << 30, 0};
  mega_prep<<<4161, 256, 0, stream>>>(T, count);

  // D2: G1 (Pstk_c = Wk_bf @ memT per k-chunk, K=8192 split-16, nIter=8)
  //   + G4 (Sstk_c = zsT @ zvlT^T per k-chunk, K=4096 split-16, nIter=4)
  // 512 blocks: exact 2-blocks/CU fill, no straggler tail.
  GJobs D2;
  D2.j[0] = {Wk_bf, memT, Pstk, nullptr, nullptr,
             8192, 8192, 8192, 0, 0, 512, 0,
             1.0f, 8192, 512, 4, 4, 0, 1, 0, 0, 256};
  D2.j[1] = {zsT, zvlT, Sstk, nullptr, nullptr,
             4096, 4096, 8192, 0, 0, 512, 0,
             1.0f, 4096, 256, 4, 4, 0, 1, 0, 0, 256};
  gemm128<<<512, 256, 0, stream>>>(D2);

  // D2.5: hsum reductions Pstk->Pred (16 slices), Sstk->Sred (16 slices)
  TJobs R;
  R.j[0] = {(const float*)Pstk, Pred, nullptr, nullptr, 16, 8192, 0, 0,   3};
  R.j[1] = {(const float*)Sstk, Sred, nullptr, nullptr, 16, 8192, 0, 128, 3};
  R.j[2] = {nullptr, nullptr, nullptr, nullptr, 0, 0, 0, 1 << 30, 0};
  R.j[3] = {nullptr, nullptr, nullptr, nullptr, 0, 0, 0, 1 << 30, 0};
  R.j[4] = {nullptr, nullptr, nullptr, nullptr, 0, 0, 0, 1 << 30, 0};
  R.j[5] = {nullptr, nullptr, nullptr, nullptr, 0, 0, 0, 1 << 30, 0};
  R.j[6] = {nullptr, nullptr, nullptr, nullptr, 0, 0, 0, 1 << 30, 0};
  R.j[7] = {nullptr, nullptr, nullptr, nullptr, 0, 0, 0, 1 << 30, 0};
  mega_prep<<<256, 256, 0, stream>>>(R, count);

  // D3: G5 (UT_h = WvT_h @ Sred^T, batched 16) + G2 (QT = WoT @ Pred^T, /16)
  GJobs D3;
  D3.j[0] = {WvT, Sred, UT, nullptr, nullptr,
             512, 512, 512, 262144, 0, 262144, 0,
             1.0f, 512, 512, 4, 4, 1, 1, 0, 0, 256};
  D3.j[1] = {WoT, Pred, QT, nullptr, nullptr,
             512, 512, 512, 0, 0, 0, 0,
             1.0f / 16.0f, 512, 512, 4, 4, 0, 1, 0, 0, 16};
  gemm128<<<272, 256, 0, stream>>>(D3);

  // D4: G6 (newmem = mem + WkT_h @ UT_h^T / count, batched 16) + G3 (vret = zq @ QT^T)
  GJobs D4;
  D4.j[0] = {WkT, UT, newmem, mem, count,
             512, 512, 512, 262144, 262144, 262144, 262144,
             1.0f, 512, 512, 4, 4, 1, 3, 0, 0, 256};
  D4.j[1] = {zq, QT, vret, nullptr, nullptr,
             512, 512, 512, 0, 0, 0, 0,
             1.0f, 512, 512, 32, 4, 0, 2, 1, 0, 128};
  gemm128<<<384, 256, 0, stream>>>(D4);
}

// Round 16
// 192.923 us; speedup vs baseline: 1.4218x; 1.0399x over previous
//
#include <hip/hip_runtime.h>

typedef unsigned short u16;
typedef __attribute__((ext_vector_type(8))) short bf16x8;
typedef __attribute__((ext_vector_type(8))) unsigned short u16x8;
typedef __attribute__((ext_vector_type(4))) float f32x4;

#define B_DIM 4096
#define D_DIM 512
#define H_DIM 16

typedef const __attribute__((address_space(1))) unsigned int* gas_t;
typedef __attribute__((address_space(3))) unsigned int* las_t;

__device__ __forceinline__ u16 f2bf(float f) {
  union { float f; unsigned u; } x;
  x.f = f;
  unsigned r = x.u + 0x7FFFu + ((x.u >> 16) & 1u);
  return (u16)(r >> 16);
}

__device__ __forceinline__ float bf2f(u16 h) {
  union { unsigned u; float f; } x;
  x.u = ((unsigned)h) << 16;
  return x.f;
}

__device__ __forceinline__ uint4 pack8(float4 v0, float4 v1) {
  union { uint4 q; u16 h[8]; } u;
  u.h[0] = f2bf(v0.x); u.h[1] = f2bf(v0.y); u.h[2] = f2bf(v0.z); u.h[3] = f2bf(v0.w);
  u.h[4] = f2bf(v1.x); u.h[5] = f2bf(v1.y); u.h[6] = f2bf(v1.z); u.h[7] = f2bf(v1.w);
  return u.q;
}

// ---- prep uber kernel (identical to measured round 9) ----
// kind 0: 64x64 LDS transpose f32->bf16 (optional out2 = row-major bf16 copy);
// kind 1: transpose with lam(conf) row-scale;
// kind 2: count reduction (1 block);
// kind 3: hsum — out[r,c] = sum_s in[r*cols + s*512 + c], bf16 in/out.
struct TJob {
  const float* in;
  void* out;
  void* out2;
  const float* conf;
  int rows, cols, tiles_x, tile_off, kind;
};
struct TJobs { TJob j[8]; };

__global__ __launch_bounds__(256) void mega_prep(TJobs J, float* __restrict__ countp) {
  __shared__ float tile[64][65];
  __shared__ float wsum[4];
  const int tid = threadIdx.x;
  int b = blockIdx.x;
  int sel = 0;
#pragma unroll
  for (int i = 1; i < 8; ++i)
    if (b >= J.j[i].tile_off) sel = i;
  TJob jb = J.j[sel];
  b -= jb.tile_off;

  if (jb.kind == 3) {  // hsum of k-stacked bf16 partials
    const u16* src = (const u16*)jb.in;
    u16* dst = (u16*)jb.out;
    const int nsum = jb.rows;
    const long long incols = jb.cols;
    const long long r = (long long)b * 4 + (tid >> 6);
    const int c = (tid & 63) * 8;
    float acc[8] = {0.f, 0.f, 0.f, 0.f, 0.f, 0.f, 0.f, 0.f};
#pragma unroll 4
    for (int s = 0; s < nsum; ++s) {
      u16x8 v = *(const u16x8*)(src + r * incols + s * 512 + c);
#pragma unroll
      for (int i = 0; i < 8; ++i) acc[i] += bf2f(v[i]);
    }
    union { uint4 q; u16 h[8]; } o;
#pragma unroll
    for (int i = 0; i < 8; ++i) o.h[i] = f2bf(acc[i]);
    *(uint4*)(dst + r * 512 + c) = o.q;
    return;
  }
  if (jb.kind == 2) {  // count
    float m = 0.f;
    for (int i = tid; i < B_DIM; i += 256) {
      float l = 1.0f - jb.in[i];
      l = fminf(fmaxf(l, 0.f), 1.f);
      m += (l > 0.3f) ? 1.f : 0.f;
    }
    for (int off = 32; off; off >>= 1) m += __shfl_down(m, off, 64);
    if ((tid & 63) == 0) wsum[tid >> 6] = m;
    __syncthreads();
    if (tid == 0) countp[0] = wsum[0] + wsum[1] + wsum[2] + wsum[3];
    return;
  }

  // transpose kinds 0/1: 64x64 tile via LDS.
  const long long c0 = (long long)(b % jb.tiles_x) * 64;
  const long long r0 = (long long)(b / jb.tiles_x) * 64;
  const int rr = tid >> 4;         // 0..15
  const int cc4 = (tid & 15) * 4;  // 0..60
#pragma unroll
  for (int i = 0; i < 4; ++i) {
    int row = i * 16 + rr;
    float4 v = *(const float4*)(jb.in + (r0 + row) * jb.cols + c0 + cc4);
    if (jb.kind == 1) {
      float l = 1.0f - jb.conf[r0 + row];
      l = fminf(fmaxf(l, 0.f), 1.f);
      float s = (l > 0.3f) ? l : 0.f;
      v.x *= s; v.y *= s; v.z *= s; v.w *= s;
    }
    tile[row][cc4] = v.x; tile[row][cc4 + 1] = v.y;
    tile[row][cc4 + 2] = v.z; tile[row][cc4 + 3] = v.w;
    if (jb.out2) {  // row-major bf16 side copy (Wk: saves a second 16 MB pass)
      union { uint2 u; u16 h[4]; } p;
      p.h[0] = f2bf(v.x); p.h[1] = f2bf(v.y); p.h[2] = f2bf(v.z); p.h[3] = f2bf(v.w);
      *(uint2*)((u16*)jb.out2 + (r0 + row) * jb.cols + c0 + cc4) = p.u;
    }
  }
  __syncthreads();
  const int orow = tid >> 2;  // 0..63
  const int seg = tid & 3;    // 16 u16 per thread
  union { uint4 q[2]; u16 h[16]; } o;
#pragma unroll
  for (int i = 0; i < 16; ++i) o.h[i] = f2bf(tile[seg * 16 + i][orow]);
  u16* outp = (u16*)jb.out + (c0 + orow) * jb.rows + r0 + seg * 16;
  *(uint4*)outp = o.q[0];
  *(uint4*)(outp + 8) = o.q[1];
}

// ---- 128x128-tile GEMM, BK=64, double-buffered, swizzled LDS ----
// 512 threads / 8 waves per block (was 256/4): each wave computes a 64x32
// sub-tile (wm = (w&1)*64, wn = (w>>1)*32, acc[4][2]). Same 64 KB LDS ->
// still 2 blocks/CU, but 16 waves/CU (25% occupancy, was 8 waves/12%) to
// hide the vmcnt(0) barrier drains and HBM latency.
// Everything else identical to the measured round-9 kernel: chunk-XOR LDS
// swizzle, global_load_lds(16B) staging, bijective XCD blockIdx swizzle,
// atomic-free k-stacked split-K partials.
// mode 1: store bf16*alpha; 2: store f32*alpha; 3: store f32 = addsrc + acc/(cnt+1e-6).
struct GJob {
  const void* A; const void* Bp; void* C;
  const float* addsrc; const float* cnt;
  long long lda, ldb, ldc, sa_b, sb_b, sc_b, sadd_b;
  float alpha;
  int K, k_chunk, tm, tn, batched, mode, aflag, bflag, nblocks;
};
struct GJobs { GJob j[2]; };

__global__ __launch_bounds__(512, 4) void gemm128(GJobs JJ) {
  __shared__ alignas(16) u16 As[2][128 * 64];
  __shared__ alignas(16) u16 Bs[2][128 * 64];

  // XCD-aware bijective swizzle (m204).
  const int nwg = gridDim.x;
  const int orig = blockIdx.x;
  const int q = nwg >> 3, r = nwg & 7;
  const int xcd = orig & 7;
  const int loc = orig >> 3;
  int b = (xcd < r ? xcd * (q + 1) : r * (q + 1) + (xcd - r) * q) + loc;

  GJob J = JJ.j[0];
  if (b >= J.nblocks) { b -= J.nblocks; J = JJ.j[1]; }

  const int tilesper = J.tm * J.tn;
  const int bz = b / tilesper;
  const int rel = b % tilesper;
  const long long m0 = (long long)(rel / J.tn) * 128;
  const long long n0 = (long long)(rel % J.tn) * 128;

  long long aoff = 0, boff = 0, coff = 0, doff = 0, k0 = 0;
  int Kl = J.K;
  if (J.batched) {
    aoff = (long long)bz * J.sa_b;
    boff = (long long)bz * J.sb_b;
    coff = (long long)bz * J.sc_b;
    doff = (long long)bz * J.sadd_b;
  } else {
    k0 = (long long)bz * J.k_chunk;
    Kl = J.k_chunk;
    coff = (long long)bz * J.sc_b;  // k-stacked partial output (no atomics)
  }

  const int tid = threadIdx.x;
  const int lane = tid & 63, wave = tid >> 6;      // wave 0..7
  const int wm = (wave & 1) * 64, wn = (wave >> 1) * 32;
  const int fm = lane & 15, fg = lane >> 4;

  auto stage = [&](u16* dst, const void* src, long long ld, long long off,
                   long long rbase, long long t, int isf32) {
    if (!isf32) {
      const u16* gb = (const u16*)src + off;
#pragma unroll
      for (int j = 0; j < 2; ++j) {
        int cc = wave * 2 + j;                     // 16 cc-units over 8 waves
        int row = cc * 8 + (lane >> 3);
        int cg = (lane & 7) ^ (row & 7);
        const u16* g = gb + (rbase + row) * ld + t + cg * 8;
        __builtin_amdgcn_global_load_lds((gas_t)(const void*)g,
                                         (las_t)(void*)(dst + cc * 512 + lane * 8),
                                         16, 0, 0);
      }
    } else {
      const float* gb = (const float*)src + off;
#pragma unroll
      for (int p = 0; p < 2; ++p) {
        int idx = p * 512 + tid;                   // 1024 chunks over 512 thr
        int row = idx >> 3, cg = idx & 7;
        const float* g = gb + (rbase + row) * ld + t + cg * 8;
        float4 v0 = *(const float4*)g;
        float4 v1 = *(const float4*)(g + 4);
        *(uint4*)&dst[row * 64 + ((cg ^ (row & 7)) * 8)] = pack8(v0, v1);
      }
    }
  };

  f32x4 acc[4][2];
#pragma unroll
  for (int i = 0; i < 4; ++i)
#pragma unroll
    for (int j = 0; j < 2; ++j) acc[i][j] = (f32x4){0.f, 0.f, 0.f, 0.f};

  const int nIter = Kl >> 6;
  stage(As[0], J.A, J.lda, aoff, m0, k0, J.aflag);
  stage(Bs[0], J.Bp, J.ldb, boff, n0, k0, J.bflag);

  for (int i = 0; i < nIter; ++i) {
    __syncthreads();  // drains current buffer's loads
    if (i + 1 < nIter) {
      long long t = k0 + (long long)(i + 1) * 64;
      stage(As[(i + 1) & 1], J.A, J.lda, aoff, m0, t, J.aflag);
      stage(Bs[(i + 1) & 1], J.Bp, J.ldb, boff, n0, t, J.bflag);
    }
    const u16* Ab = As[i & 1];
    const u16* Bb = Bs[i & 1];
#pragma unroll
    for (int kcc = 0; kcc < 8; kcc += 4) {
      bf16x8 af[4], bfr[2];
#pragma unroll
      for (int fi = 0; fi < 4; ++fi) {
        int row = wm + fi * 16 + fm;
        af[fi] = *(const bf16x8*)&Ab[row * 64 + (((kcc + fg) ^ (row & 7)) * 8)];
      }
#pragma unroll
      for (int fj = 0; fj < 2; ++fj) {
        int row = wn + fj * 16 + fm;
        bfr[fj] = *(const bf16x8*)&Bb[row * 64 + (((kcc + fg) ^ (row & 7)) * 8)];
      }
#pragma unroll
      for (int fi = 0; fi < 4; ++fi)
#pragma unroll
        for (int fj = 0; fj < 2; ++fj)
          acc[fi][fj] = __builtin_amdgcn_mfma_f32_16x16x32_bf16(af[fi], bfr[fj], acc[fi][fj], 0, 0, 0);
    }
  }

  float inv = (J.mode == 3) ? 1.0f / (*J.cnt + 1e-6f) : 0.0f;
#pragma unroll
  for (int fi = 0; fi < 4; ++fi) {
#pragma unroll
    for (int r2 = 0; r2 < 4; ++r2) {
      long long row = m0 + wm + fi * 16 + fg * 4 + r2;
#pragma unroll
      for (int fj = 0; fj < 2; ++fj) {
        long long col = n0 + wn + fj * 16 + fm;
        long long idx = row * J.ldc + col;
        float v = acc[fi][fj][r2];
        if (J.mode == 1) {
          ((u16*)J.C)[coff + idx] = f2bf(v * J.alpha);
        } else if (J.mode == 2) {
          ((float*)J.C)[coff + idx] = v * J.alpha;
        } else {
          ((float*)J.C)[coff + idx] = J.addsrc[doff + idx] + v * inv;
        }
      }
    }
  }
}

extern "C" void kernel_launch(void* const* d_in, const int* in_sizes, int n_in,
                              void* d_out, int out_size, void* d_ws, size_t ws_size,
                              hipStream_t stream) {
  (void)in_sizes; (void)n_in; (void)out_size; (void)ws_size;
  const float* zq   = (const float*)d_in[0];
  const float* zs   = (const float*)d_in[1];
  const float* zv   = (const float*)d_in[2];
  const float* conf = (const float*)d_in[3];
  const float* Wk   = (const float*)d_in[4];
  const float* Wv   = (const float*)d_in[5];
  const float* Wo   = (const float*)d_in[6];
  const float* mem  = (const float*)d_in[7];

  float* vret = (float*)d_out;                      // (B, D)
  float* newmem = vret + (long long)B_DIM * D_DIM;  // (H, D, D)

  float* count = (float*)d_ws;
  u16* bb = (u16*)((char*)d_ws + 256);
  u16* zsT   = bb;              // 512 x 4096
  u16* zvlT  = bb + 2097152;    // 512 x 4096 (lam-scaled)
  u16* WkT   = bb + 4194304;    // 8192 x 512
  u16* WvT   = bb + 8388608;    // 8192 x 512
  u16* memT  = bb + 12582912;   // 512 x 8192
  u16* WoT   = bb + 16777216;   // 512 x 512
  u16* Wk_bf = bb + 17039360;   // 512 x 8192 row-major (dual-output of Wk transpose)
  u16* Pstk  = bb + 21233664;   // 512 x 8192: [d', chunk*512+e] partials (16 chunks)
  u16* Sstk  = bb + 25427968;   // 512 x 8192: [d1, chunk*512+d2] partials (16 chunks)
  u16* Pred  = bb + 29622272;   // 512 x 512  = sum_c P_c
  u16* Sred  = bb + 29884416;   // 512 x 512  = sum_c S_c
  u16* QT    = bb + 30146560;   // 512 x 512 (Q^T, /16 folded)
  u16* UT    = bb + 30408704;   // 16 x 512 x 512 (U_h^T)

  // D1: 64x64 transposes (Wk dual-output) + count.
  TJobs T;
  T.j[0] = {zs,  zsT,  nullptr, nullptr, 4096, 512,  8,   0,    0};
  T.j[1] = {zv,  zvlT, nullptr, conf,    4096, 512,  8,   512,  1};
  T.j[2] = {Wk,  WkT,  Wk_bf,   nullptr, 512,  8192, 128, 1024, 0};
  T.j[3] = {Wv,  WvT,  nullptr, nullptr, 512,  8192, 128, 2048, 0};
  T.j[4] = {mem, memT, nullptr, nullptr, 8192, 512,  8,   3072, 0};
  T.j[5] = {Wo,  WoT,  nullptr, nullptr, 512,  512,  8,   4096, 0};
  T.j[6] = {conf, nullptr, nullptr, nullptr, 0, 0, 0,     4160, 2};  // 1 block
  T.j[7] = {nullptr, nullptr, nullptr, nullptr, 0, 0, 0, 1 << 30, 0};
  mega_prep<<<4161, 256, 0, stream>>>(T, count);

  // D2: G1 (Pstk_c = Wk_bf @ memT per k-chunk, K=8192 split-16, nIter=8)
  //   + G4 (Sstk_c = zsT @ zvlT^T per k-chunk, K=4096 split-16, nIter=4)
  // 512 blocks x 512 thr: exact 2-blocks/CU fill, 16 waves/CU.
  GJobs D2;
  D2.j[0] = {Wk_bf, memT, Pstk, nullptr, nullptr,
             8192, 8192, 8192, 0, 0, 512, 0,
             1.0f, 8192, 512, 4, 4, 0, 1, 0, 0, 256};
  D2.j[1] = {zsT, zvlT, Sstk, nullptr, nullptr,
             4096, 4096, 8192, 0, 0, 512, 0,
             1.0f, 4096, 256, 4, 4, 0, 1, 0, 0, 256};
  gemm128<<<512, 512, 0, stream>>>(D2);

  // D2.5: hsum reductions Pstk->Pred (16 slices), Sstk->Sred (16 slices)
  TJobs R;
  R.j[0] = {(const float*)Pstk, Pred, nullptr, nullptr, 16, 8192, 0, 0,   3};
  R.j[1] = {(const float*)Sstk, Sred, nullptr, nullptr, 16, 8192, 0, 128, 3};
  R.j[2] = {nullptr, nullptr, nullptr, nullptr, 0, 0, 0, 1 << 30, 0};
  R.j[3] = {nullptr, nullptr, nullptr, nullptr, 0, 0, 0, 1 << 30, 0};
  R.j[4] = {nullptr, nullptr, nullptr, nullptr, 0, 0, 0, 1 << 30, 0};
  R.j[5] = {nullptr, nullptr, nullptr, nullptr, 0, 0, 0, 1 << 30, 0};
  R.j[6] = {nullptr, nullptr, nullptr, nullptr, 0, 0, 0, 1 << 30, 0};
  R.j[7] = {nullptr, nullptr, nullptr, nullptr, 0, 0, 0, 1 << 30, 0};
  mega_prep<<<256, 256, 0, stream>>>(R, count);

  // D3: G5 (UT_h = WvT_h @ Sred^T, batched 16) + G2 (QT = WoT @ Pred^T, /16)
  GJobs D3;
  D3.j[0] = {WvT, Sred, UT, nullptr, nullptr,
             512, 512, 512, 262144, 0, 262144, 0,
             1.0f, 512, 512, 4, 4, 1, 1, 0, 0, 256};
  D3.j[1] = {WoT, Pred, QT, nullptr, nullptr,
             512, 512, 512, 0, 0, 0, 0,
             1.0f / 16.0f, 512, 512, 4, 4, 0, 1, 0, 0, 16};
  gemm128<<<272, 512, 0, stream>>>(D3);

  // D4: G6 (newmem = mem + WkT_h @ UT_h^T / count, batched 16) + G3 (vret = zq @ QT^T)
  GJobs D4;
  D4.j[0] = {WkT, UT, newmem, mem, count,
             512, 512, 512, 262144, 262144, 262144, 262144,
             1.0f, 512, 512, 4, 4, 1, 3, 0, 0, 256};
  D4.j[1] = {zq, QT, vret, nullptr, nullptr,
             512, 512, 512, 0, 0, 0, 0,
             1.0f, 512, 512, 32, 4, 0, 2, 1, 0, 128};
  gemm128<<<384, 512, 0, stream>>>(D4);
}

// Round 17
// 192.015 us; speedup vs baseline: 1.4285x; 1.0047x over previous
//
#include <hip/hip_runtime.h>

typedef unsigned short u16;
typedef __attribute__((ext_vector_type(8))) short bf16x8;
typedef __attribute__((ext_vector_type(8))) unsigned short u16x8;
typedef __attribute__((ext_vector_type(4))) float f32x4;

#define B_DIM 4096
#define D_DIM 512
#define H_DIM 16

typedef const __attribute__((address_space(1))) unsigned int* gas_t;
typedef __attribute__((address_space(3))) unsigned int* las_t;

__device__ __forceinline__ u16 f2bf(float f) {
  union { float f; unsigned u; } x;
  x.f = f;
  unsigned r = x.u + 0x7FFFu + ((x.u >> 16) & 1u);
  return (u16)(r >> 16);
}

__device__ __forceinline__ float bf2f(u16 h) {
  union { unsigned u; float f; } x;
  x.u = ((unsigned)h) << 16;
  return x.f;
}

__device__ __forceinline__ uint4 pack8(float4 v0, float4 v1) {
  union { uint4 q; u16 h[8]; } u;
  u.h[0] = f2bf(v0.x); u.h[1] = f2bf(v0.y); u.h[2] = f2bf(v0.z); u.h[3] = f2bf(v0.w);
  u.h[4] = f2bf(v1.x); u.h[5] = f2bf(v1.y); u.h[6] = f2bf(v1.z); u.h[7] = f2bf(v1.w);
  return u.q;
}

// ---- prep uber kernel (identical to measured round 16) ----
// kind 0: 64x64 LDS transpose f32->bf16 (optional out2 = row-major bf16 copy);
// kind 1: transpose with lam(conf) row-scale;
// kind 2: count reduction (1 block);
// kind 3: hsum — out[r,c] = sum_s in[r*cols + s*512 + c], bf16 in/out.
struct TJob {
  const float* in;
  void* out;
  void* out2;
  const float* conf;
  int rows, cols, tiles_x, tile_off, kind;
};
struct TJobs { TJob j[8]; };

__global__ __launch_bounds__(256) void mega_prep(TJobs J, float* __restrict__ countp) {
  __shared__ float tile[64][65];
  __shared__ float wsum[4];
  const int tid = threadIdx.x;
  int b = blockIdx.x;
  int sel = 0;
#pragma unroll
  for (int i = 1; i < 8; ++i)
    if (b >= J.j[i].tile_off) sel = i;
  TJob jb = J.j[sel];
  b -= jb.tile_off;

  if (jb.kind == 3) {  // hsum of k-stacked bf16 partials
    const u16* src = (const u16*)jb.in;
    u16* dst = (u16*)jb.out;
    const int nsum = jb.rows;
    const long long incols = jb.cols;
    const long long r = (long long)b * 4 + (tid >> 6);
    const int c = (tid & 63) * 8;
    float acc[8] = {0.f, 0.f, 0.f, 0.f, 0.f, 0.f, 0.f, 0.f};
#pragma unroll 4
    for (int s = 0; s < nsum; ++s) {
      u16x8 v = *(const u16x8*)(src + r * incols + s * 512 + c);
#pragma unroll
      for (int i = 0; i < 8; ++i) acc[i] += bf2f(v[i]);
    }
    union { uint4 q; u16 h[8]; } o;
#pragma unroll
    for (int i = 0; i < 8; ++i) o.h[i] = f2bf(acc[i]);
    *(uint4*)(dst + r * 512 + c) = o.q;
    return;
  }
  if (jb.kind == 2) {  // count
    float m = 0.f;
    for (int i = tid; i < B_DIM; i += 256) {
      float l = 1.0f - jb.in[i];
      l = fminf(fmaxf(l, 0.f), 1.f);
      m += (l > 0.3f) ? 1.f : 0.f;
    }
    for (int off = 32; off; off >>= 1) m += __shfl_down(m, off, 64);
    if ((tid & 63) == 0) wsum[tid >> 6] = m;
    __syncthreads();
    if (tid == 0) countp[0] = wsum[0] + wsum[1] + wsum[2] + wsum[3];
    return;
  }

  // transpose kinds 0/1: 64x64 tile via LDS.
  const long long c0 = (long long)(b % jb.tiles_x) * 64;
  const long long r0 = (long long)(b / jb.tiles_x) * 64;
  const int rr = tid >> 4;         // 0..15
  const int cc4 = (tid & 15) * 4;  // 0..60
#pragma unroll
  for (int i = 0; i < 4; ++i) {
    int row = i * 16 + rr;
    float4 v = *(const float4*)(jb.in + (r0 + row) * jb.cols + c0 + cc4);
    if (jb.kind == 1) {
      float l = 1.0f - jb.conf[r0 + row];
      l = fminf(fmaxf(l, 0.f), 1.f);
      float s = (l > 0.3f) ? l : 0.f;
      v.x *= s; v.y *= s; v.z *= s; v.w *= s;
    }
    tile[row][cc4] = v.x; tile[row][cc4 + 1] = v.y;
    tile[row][cc4 + 2] = v.z; tile[row][cc4 + 3] = v.w;
    if (jb.out2) {  // row-major bf16 side copy (Wk: saves a second 16 MB pass)
      union { uint2 u; u16 h[4]; } p;
      p.h[0] = f2bf(v.x); p.h[1] = f2bf(v.y); p.h[2] = f2bf(v.z); p.h[3] = f2bf(v.w);
      *(uint2*)((u16*)jb.out2 + (r0 + row) * jb.cols + c0 + cc4) = p.u;
    }
  }
  __syncthreads();
  const int orow = tid >> 2;  // 0..63
  const int seg = tid & 3;    // 16 u16 per thread
  union { uint4 q[2]; u16 h[16]; } o;
#pragma unroll
  for (int i = 0; i < 16; ++i) o.h[i] = f2bf(tile[seg * 16 + i][orow]);
  u16* outp = (u16*)jb.out + (c0 + orow) * jb.rows + r0 + seg * 16;
  *(uint4*)outp = o.q[0];
  *(uint4*)(outp + 8) = o.q[1];
}

// ---- 128x128-tile GEMM, BK=64, double-buffered, swizzled LDS ----
// 1024 threads / 16 waves per block (was 512/8): each wave computes a 32x32
// sub-tile (wm = (w&3)*32, wn = (w>>2)*32, acc[2][2]). Same 64 KB LDS ->
// still 2 blocks/CU, but 32 waves/CU (100% of wave slots, was 16) to hide
// the vmcnt(0) barrier drains and HBM latency. __launch_bounds__(1024,8)
// caps VGPR at 64 (live data regs ~32: acc 16 + frags 16), the requirement
// for 8 waves/SIMD.
// Everything else identical to the measured round-16 kernel: chunk-XOR LDS
// swizzle, global_load_lds(16B) staging, bijective XCD blockIdx swizzle,
// atomic-free k-stacked split-K partials.
// mode 1: store bf16*alpha; 2: store f32*alpha; 3: store f32 = addsrc + acc/(cnt+1e-6).
struct GJob {
  const void* A; const void* Bp; void* C;
  const float* addsrc; const float* cnt;
  long long lda, ldb, ldc, sa_b, sb_b, sc_b, sadd_b;
  float alpha;
  int K, k_chunk, tm, tn, batched, mode, aflag, bflag, nblocks;
};
struct GJobs { GJob j[2]; };

__global__ __launch_bounds__(1024, 8) void gemm128(GJobs JJ) {
  __shared__ alignas(16) u16 As[2][128 * 64];
  __shared__ alignas(16) u16 Bs[2][128 * 64];

  // XCD-aware bijective swizzle (m204).
  const int nwg = gridDim.x;
  const int orig = blockIdx.x;
  const int q = nwg >> 3, r = nwg & 7;
  const int xcd = orig & 7;
  const int loc = orig >> 3;
  int b = (xcd < r ? xcd * (q + 1) : r * (q + 1) + (xcd - r) * q) + loc;

  GJob J = JJ.j[0];
  if (b >= J.nblocks) { b -= J.nblocks; J = JJ.j[1]; }

  const int tilesper = J.tm * J.tn;
  const int bz = b / tilesper;
  const int rel = b % tilesper;
  const long long m0 = (long long)(rel / J.tn) * 128;
  const long long n0 = (long long)(rel % J.tn) * 128;

  long long aoff = 0, boff = 0, coff = 0, doff = 0, k0 = 0;
  int Kl = J.K;
  if (J.batched) {
    aoff = (long long)bz * J.sa_b;
    boff = (long long)bz * J.sb_b;
    coff = (long long)bz * J.sc_b;
    doff = (long long)bz * J.sadd_b;
  } else {
    k0 = (long long)bz * J.k_chunk;
    Kl = J.k_chunk;
    coff = (long long)bz * J.sc_b;  // k-stacked partial output (no atomics)
  }

  const int tid = threadIdx.x;
  const int lane = tid & 63, wave = tid >> 6;      // wave 0..15
  const int wm = (wave & 3) * 32, wn = (wave >> 2) * 32;
  const int fm = lane & 15, fg = lane >> 4;

  auto stage = [&](u16* dst, const void* src, long long ld, long long off,
                   long long rbase, long long t, int isf32) {
    if (!isf32) {
      const u16* gb = (const u16*)src + off;
      {
        int cc = wave;                             // 16 cc-units over 16 waves
        int row = cc * 8 + (lane >> 3);
        int cg = (lane & 7) ^ (row & 7);
        const u16* g = gb + (rbase + row) * ld + t + cg * 8;
        __builtin_amdgcn_global_load_lds((gas_t)(const void*)g,
                                         (las_t)(void*)(dst + cc * 512 + lane * 8),
                                         16, 0, 0);
      }
    } else {
      const float* gb = (const float*)src + off;
      {
        int idx = tid;                             // 1024 chunks over 1024 thr
        int row = idx >> 3, cg = idx & 7;
        const float* g = gb + (rbase + row) * ld + t + cg * 8;
        float4 v0 = *(const float4*)g;
        float4 v1 = *(const float4*)(g + 4);
        *(uint4*)&dst[row * 64 + ((cg ^ (row & 7)) * 8)] = pack8(v0, v1);
      }
    }
  };

  f32x4 acc[2][2];
#pragma unroll
  for (int i = 0; i < 2; ++i)
#pragma unroll
    for (int j = 0; j < 2; ++j) acc[i][j] = (f32x4){0.f, 0.f, 0.f, 0.f};

  const int nIter = Kl >> 6;
  stage(As[0], J.A, J.lda, aoff, m0, k0, J.aflag);
  stage(Bs[0], J.Bp, J.ldb, boff, n0, k0, J.bflag);

  for (int i = 0; i < nIter; ++i) {
    __syncthreads();  // drains current buffer's loads
    if (i + 1 < nIter) {
      long long t = k0 + (long long)(i + 1) * 64;
      stage(As[(i + 1) & 1], J.A, J.lda, aoff, m0, t, J.aflag);
      stage(Bs[(i + 1) & 1], J.Bp, J.ldb, boff, n0, t, J.bflag);
    }
    const u16* Ab = As[i & 1];
    const u16* Bb = Bs[i & 1];
#pragma unroll
    for (int kcc = 0; kcc < 8; kcc += 4) {
      bf16x8 af[2], bfr[2];
#pragma unroll
      for (int fi = 0; fi < 2; ++fi) {
        int row = wm + fi * 16 + fm;
        af[fi] = *(const bf16x8*)&Ab[row * 64 + (((kcc + fg) ^ (row & 7)) * 8)];
      }
#pragma unroll
      for (int fj = 0; fj < 2; ++fj) {
        int row = wn + fj * 16 + fm;
        bfr[fj] = *(const bf16x8*)&Bb[row * 64 + (((kcc + fg) ^ (row & 7)) * 8)];
      }
#pragma unroll
      for (int fi = 0; fi < 2; ++fi)
#pragma unroll
        for (int fj = 0; fj < 2; ++fj)
          acc[fi][fj] = __builtin_amdgcn_mfma_f32_16x16x32_bf16(af[fi], bfr[fj], acc[fi][fj], 0, 0, 0);
    }
  }

  float inv = (J.mode == 3) ? 1.0f / (*J.cnt + 1e-6f) : 0.0f;
#pragma unroll
  for (int fi = 0; fi < 2; ++fi) {
#pragma unroll
    for (int r2 = 0; r2 < 4; ++r2) {
      long long row = m0 + wm + fi * 16 + fg * 4 + r2;
#pragma unroll
      for (int fj = 0; fj < 2; ++fj) {
        long long col = n0 + wn + fj * 16 + fm;
        long long idx = row * J.ldc + col;
        float v = acc[fi][fj][r2];
        if (J.mode == 1) {
          ((u16*)J.C)[coff + idx] = f2bf(v * J.alpha);
        } else if (J.mode == 2) {
          ((float*)J.C)[coff + idx] = v * J.alpha;
        } else {
          ((float*)J.C)[coff + idx] = J.addsrc[doff + idx] + v * inv;
        }
      }
    }
  }
}

extern "C" void kernel_launch(void* const* d_in, const int* in_sizes, int n_in,
                              void* d_out, int out_size, void* d_ws, size_t ws_size,
                              hipStream_t stream) {
  (void)in_sizes; (void)n_in; (void)out_size; (void)ws_size;
  const float* zq   = (const float*)d_in[0];
  const float* zs   = (const float*)d_in[1];
  const float* zv   = (const float*)d_in[2];
  const float* conf = (const float*)d_in[3];
  const float* Wk   = (const float*)d_in[4];
  const float* Wv   = (const float*)d_in[5];
  const float* Wo   = (const float*)d_in[6];
  const float* mem  = (const float*)d_in[7];

  float* vret = (float*)d_out;                      // (B, D)
  float* newmem = vret + (long long)B_DIM * D_DIM;  // (H, D, D)

  float* count = (float*)d_ws;
  u16* bb = (u16*)((char*)d_ws + 256);
  u16* zsT   = bb;              // 512 x 4096
  u16* zvlT  = bb + 2097152;    // 512 x 4096 (lam-scaled)
  u16* WkT   = bb + 4194304;    // 8192 x 512
  u16* WvT   = bb + 8388608;    // 8192 x 512
  u16* memT  = bb + 12582912;   // 512 x 8192
  u16* WoT   = bb + 16777216;   // 512 x 512
  u16* Wk_bf = bb + 17039360;   // 512 x 8192 row-major (dual-output of Wk transpose)
  u16* Pstk  = bb + 21233664;   // 512 x 8192: [d', chunk*512+e] partials (16 chunks)
  u16* Sstk  = bb + 25427968;   // 512 x 8192: [d1, chunk*512+d2] partials (16 chunks)
  u16* Pred  = bb + 29622272;   // 512 x 512  = sum_c P_c
  u16* Sred  = bb + 29884416;   // 512 x 512  = sum_c S_c
  u16* QT    = bb + 30146560;   // 512 x 512 (Q^T, /16 folded)
  u16* UT    = bb + 30408704;   // 16 x 512 x 512 (U_h^T)

  // D1: 64x64 transposes (Wk dual-output) + count.
  TJobs T;
  T.j[0] = {zs,  zsT,  nullptr, nullptr, 4096, 512,  8,   0,    0};
  T.j[1] = {zv,  zvlT, nullptr, conf,    4096, 512,  8,   512,  1};
  T.j[2] = {Wk,  WkT,  Wk_bf,   nullptr, 512,  8192, 128, 1024, 0};
  T.j[3] = {Wv,  WvT,  nullptr, nullptr, 512,  8192, 128, 2048, 0};
  T.j[4] = {mem, memT, nullptr, nullptr, 8192, 512,  8,   3072, 0};
  T.j[5] = {Wo,  WoT,  nullptr, nullptr, 512,  512,  8,   4096, 0};
  T.j[6] = {conf, nullptr, nullptr, nullptr, 0, 0, 0,     4160, 2};  // 1 block
  T.j[7] = {nullptr, nullptr, nullptr, nullptr, 0, 0, 0, 1 << 30, 0};
  mega_prep<<<4161, 256, 0, stream>>>(T, count);

  // D2: G1 (Pstk_c = Wk_bf @ memT per k-chunk, K=8192 split-16, nIter=8)
  //   + G4 (Sstk_c = zsT @ zvlT^T per k-chunk, K=4096 split-16, nIter=4)
  // 512 blocks x 1024 thr: exact 2-blocks/CU fill, 32 waves/CU.
  GJobs D2;
  D2.j[0] = {Wk_bf, memT, Pstk, nullptr, nullptr,
             8192, 8192, 8192, 0, 0, 512, 0,
             1.0f, 8192, 512, 4, 4, 0, 1, 0, 0, 256};
  D2.j[1] = {zsT, zvlT, Sstk, nullptr, nullptr,
             4096, 4096, 8192, 0, 0, 512, 0,
             1.0f, 4096, 256, 4, 4, 0, 1, 0, 0, 256};
  gemm128<<<512, 1024, 0, stream>>>(D2);

  // D2.5: hsum reductions Pstk->Pred (16 slices), Sstk->Sred (16 slices)
  TJobs R;
  R.j[0] = {(const float*)Pstk, Pred, nullptr, nullptr, 16, 8192, 0, 0,   3};
  R.j[1] = {(const float*)Sstk, Sred, nullptr, nullptr, 16, 8192, 0, 128, 3};
  R.j[2] = {nullptr, nullptr, nullptr, nullptr, 0, 0, 0, 1 << 30, 0};
  R.j[3] = {nullptr, nullptr, nullptr, nullptr, 0, 0, 0, 1 << 30, 0};
  R.j[4] = {nullptr, nullptr, nullptr, nullptr, 0, 0, 0, 1 << 30, 0};
  R.j[5] = {nullptr, nullptr, nullptr, nullptr, 0, 0, 0, 1 << 30, 0};
  R.j[6] = {nullptr, nullptr, nullptr, nullptr, 0, 0, 0, 1 << 30, 0};
  R.j[7] = {nullptr, nullptr, nullptr, nullptr, 0, 0, 0, 1 << 30, 0};
  mega_prep<<<256, 256, 0, stream>>>(R, count);

  // D3: G5 (UT_h = WvT_h @ Sred^T, batched 16) + G2 (QT = WoT @ Pred^T, /16)
  GJobs D3;
  D3.j[0] = {WvT, Sred, UT, nullptr, nullptr,
             512, 512, 512, 262144, 0, 262144, 0,
             1.0f, 512, 512, 4, 4, 1, 1, 0, 0, 256};
  D3.j[1] = {WoT, Pred, QT, nullptr, nullptr,
             512, 512, 512, 0, 0, 0, 0,
             1.0f / 16.0f, 512, 512, 4, 4, 0, 1, 0, 0, 16};
  gemm128<<<272, 1024, 0, stream>>>(D3);

  // D4: G6 (newmem = mem + WkT_h @ UT_h^T / count, batched 16) + G3 (vret = zq @ QT^T)
  GJobs D4;
  D4.j[0] = {WkT, UT, newmem, mem, count,
             512, 512, 512, 262144, 262144, 262144, 262144,
             1.0f, 512, 512, 4, 4, 1, 3, 0, 0, 256};
  D4.j[1] = {zq, QT, vret, nullptr, nullptr,
             512, 512, 512, 0, 0, 0, 0,
             1.0f, 512, 512, 32, 4, 0, 2, 1, 0, 128};
  gemm128<<<384, 1024, 0, stream>>>(D4);
}